// Round 1
// baseline (4882.402 us; speedup 1.0000x reference)
//
#include <hip/hip_runtime.h>
#include <hip/hip_bf16.h>

#define DEVI __device__ __forceinline__

static constexpr int Bn = 8, Ln = 128;
static constexpr int EMBc = 300, POSc = 30, INc = 330;
static constexpr int Hc = 256, H2c = 512, G4 = 1024, G3 = 1536;
static constexpr int NBIOc = 9, NLABc = 10;
static constexpr float NEGc = -100000000000.0f;

DEVI float sigf(float x) { return 1.0f / (1.0f + __expf(-x)); }

// ---------------- embedding: x = concat(emb[tokens], pos_emb[pos]) ----------------
__global__ void k_embed(const int* __restrict__ tok, const int* __restrict__ pos,
                        const float* __restrict__ emb, const float* __restrict__ pemb,
                        float* __restrict__ x) {
    int i = blockIdx.x * 256 + threadIdx.x;
    if (i >= Bn * Ln * INc) return;
    int bl = i / INc, c = i - bl * INc;
    float v;
    if (c < EMBc) v = emb[tok[bl] * EMBc + c];
    else          v = pemb[pos[bl] * POSc + (c - EMBc)];
    x[i] = v;
}

// ---------------- generic C[M,N] = A[M,K](lda) @ B[N,K](ldb)^T + bias ----------------
// 64x64 tile, 256 threads, 4x4 micro-tile per thread.
__global__ __launch_bounds__(256) void k_gemm_bt(
    const float* __restrict__ A, int lda, const float* __restrict__ Bm, int ldb,
    const float* __restrict__ bias, float* __restrict__ C, int M, int N, int K) {
    __shared__ float As[64][17];
    __shared__ float Bs[64][17];
    int tid = threadIdx.x;
    int tx = tid & 15, ty = tid >> 4;
    int m0 = blockIdx.y * 64, n0 = blockIdx.x * 64;
    float acc[4][4] = {};
    for (int k0 = 0; k0 < K; k0 += 16) {
#pragma unroll
        for (int i = 0; i < 4; i++) {
            int idx = tid + i * 256;
            int r = idx >> 4, c = idx & 15;
            int mm = m0 + r, kk = k0 + c;
            As[r][c] = (mm < M && kk < K) ? A[(size_t)mm * lda + kk] : 0.f;
            int nn = n0 + r;
            Bs[r][c] = (nn < N && kk < K) ? Bm[(size_t)nn * ldb + kk] : 0.f;
        }
        __syncthreads();
#pragma unroll
        for (int kk = 0; kk < 16; kk++) {
            float a[4], bb[4];
#pragma unroll
            for (int i = 0; i < 4; i++) { a[i] = As[ty * 4 + i][kk]; bb[i] = Bs[tx * 4 + i][kk]; }
#pragma unroll
            for (int i = 0; i < 4; i++)
#pragma unroll
                for (int j = 0; j < 4; j++) acc[i][j] += a[i] * bb[j];
        }
        __syncthreads();
    }
#pragma unroll
    for (int i = 0; i < 4; i++) {
        int mm = m0 + ty * 4 + i;
        if (mm >= M) continue;
#pragma unroll
        for (int j = 0; j < 4; j++) {
            int nn = n0 + tx * 4 + j;
            if (nn < N) C[(size_t)mm * N + nn] = acc[i][j] + (bias ? bias[nn] : 0.f);
        }
    }
}

// ---------------- bidirectional masked LSTM scan ----------------
// grid = 16 blocks: block (d*8+b) runs the full 128-step scan for (direction d, batch b).
__global__ __launch_bounds__(1024) void k_lstm(
    const float* __restrict__ XpreF, const float* __restrict__ XpreB,
    const float* __restrict__ WhhF, const float* __restrict__ WhhB,
    const float* __restrict__ mask, float* __restrict__ Henc) {
    int blk = blockIdx.x;
    int d = blk >> 3, b = blk & 7;
    const float* Xpre = d ? XpreB : XpreF;
    const float* Whh  = d ? WhhB : WhhF;
    __shared__ __align__(16) float h[Hc];
    __shared__ float c[Hc];
    __shared__ float gates[G4];
    int tid = threadIdx.x;
    if (tid < Hc) { h[tid] = 0.f; c[tid] = 0.f; }
    __syncthreads();
    const float4* wr = (const float4*)(Whh + (size_t)tid * Hc);
    for (int s = 0; s < Ln; s++) {
        int t = d ? (Ln - 1 - s) : s;
        float acc = Xpre[(size_t)(b * Ln + t) * G4 + tid];
        const float4* h4 = (const float4*)h;
#pragma unroll 8
        for (int k = 0; k < Hc / 4; k++) {
            float4 w = wr[k], hh = h4[k];
            acc += w.x * hh.x + w.y * hh.y + w.z * hh.z + w.w * hh.w;
        }
        gates[tid] = acc;
        __syncthreads();
        if (tid < Hc) {
            float iv = sigf(gates[tid]);
            float fv = sigf(gates[Hc + tid]);
            float gv = tanhf(gates[2 * Hc + tid]);
            float ov = sigf(gates[3 * Hc + tid]);
            float cn = fv * c[tid] + iv * gv;
            float hn = ov * tanhf(cn);
            float m = mask[b * Ln + t];
            float hv = m * hn + (1.f - m) * h[tid];
            c[tid] = m * cn + (1.f - m) * c[tid];
            h[tid] = hv;
            Henc[(size_t)(b * Ln + t) * H2c + d * Hc + tid] = hv * m;
        }
        __syncthreads();
    }
}

// ---------------- softmax over 9 classes, per row ----------------
__global__ void k_softmax9(const float* __restrict__ lg, float* __restrict__ pr) {
    int r = blockIdx.x * 256 + threadIdx.x;
    if (r >= Bn * Ln) return;
    float v[NBIOc], mx = -3.4e38f;
#pragma unroll
    for (int k = 0; k < NBIOc; k++) { v[k] = lg[r * NBIOc + k]; mx = fmaxf(mx, v[k]); }
    float s = 0.f;
#pragma unroll
    for (int k = 0; k < NBIOc; k++) { v[k] = __expf(v[k] - mx); s += v[k]; }
    float inv = 1.f / s;
#pragma unroll
    for (int k = 0; k < NBIOc; k++) pr[r * NBIOc + k] = v[k] * inv;
}

// ---------------- log_softmax over 9 classes * mask, per row ----------------
__global__ void k_logsoftmax9(const float* __restrict__ lg, const float* __restrict__ mask,
                              float* __restrict__ outp) {
    int r = blockIdx.x * 256 + threadIdx.x;
    if (r >= Bn * Ln) return;
    float v[NBIOc], mx = -3.4e38f;
#pragma unroll
    for (int k = 0; k < NBIOc; k++) { v[k] = lg[r * NBIOc + k]; mx = fmaxf(mx, v[k]); }
    float s = 0.f;
#pragma unroll
    for (int k = 0; k < NBIOc; k++) s += __expf(v[k] - mx);
    float lse = mx + __logf(s);
    float m = mask[r];
#pragma unroll
    for (int k = 0; k < NBIOc; k++) outp[r * NBIOc + k] = (v[k] - lse) * m;
}

// ---------------- pair scores with masked max over t ----------------
// block = (b,s); 128 threads, thread = t. prob_Cr[b,s,k] = max_t where(m3>0, sigmoid, NEG)
__global__ __launch_bounds__(128) void k_pairmax(
    const float* __restrict__ Ap, const float* __restrict__ B2,
    const float* __restrict__ bL, const float* __restrict__ WCr,
    const float* __restrict__ bCr, const float* __restrict__ mask,
    float* __restrict__ probCr) {
    int bs = blockIdx.x;
    int b = bs >> 7;
    __shared__ __align__(16) float As[H2c];
    __shared__ float red[NLABc][128];
    int tid = threadIdx.x;
    for (int i = tid; i < H2c; i += 128) As[i] = Ap[(size_t)bs * H2c + i] + bL[i];
    __syncthreads();
    int t = tid;
    float m3 = mask[bs] * mask[b * Ln + t];
    float outv[NLABc];
    if (m3 > 0.f) {
        float4 acc[NLABc];
#pragma unroll
        for (int k = 0; k < NLABc; k++) acc[k] = make_float4(0.f, 0.f, 0.f, 0.f);
        const float4* B4 = (const float4*)(B2 + (size_t)(b * Ln + t) * H2c);
        const float4* A4 = (const float4*)As;
        for (int q = 0; q < H2c / 4; q++) {
            float4 a = A4[q], bb = B4[q];
            float4 e;
            e.x = fmaxf(a.x + bb.x, 0.f);
            e.y = fmaxf(a.y + bb.y, 0.f);
            e.z = fmaxf(a.z + bb.z, 0.f);
            e.w = fmaxf(a.w + bb.w, 0.f);
#pragma unroll
            for (int k = 0; k < NLABc; k++) {
                float4 w = *(const float4*)(WCr + k * H2c + q * 4);
                acc[k].x += e.x * w.x; acc[k].y += e.y * w.y;
                acc[k].z += e.z * w.z; acc[k].w += e.w * w.w;
            }
        }
#pragma unroll
        for (int k = 0; k < NLABc; k++)
            outv[k] = sigf(acc[k].x + acc[k].y + acc[k].z + acc[k].w + bCr[k]);
    } else {
#pragma unroll
        for (int k = 0; k < NLABc; k++) outv[k] = NEGc;
    }
#pragma unroll
    for (int k = 0; k < NLABc; k++) red[k][tid] = outv[k];
    __syncthreads();
    for (int off = 64; off >= 1; off >>= 1) {
        if (tid < off) {
#pragma unroll
            for (int k = 0; k < NLABc; k++) red[k][tid] = fmaxf(red[k][tid], red[k][tid + off]);
        }
        __syncthreads();
    }
    if (tid < NLABc) probCr[bs * NLABc + tid] = red[tid][0];
}

// ---------------- full pair scores * m3 (final output) ----------------
__global__ __launch_bounds__(128) void k_pairfull(
    const float* __restrict__ Ap, const float* __restrict__ B2,
    const float* __restrict__ bL, const float* __restrict__ WCr,
    const float* __restrict__ bCr, const float* __restrict__ mask,
    float* __restrict__ outCr) {
    int bs = blockIdx.x;
    int b = bs >> 7;
    __shared__ __align__(16) float As[H2c];
    int tid = threadIdx.x;
    for (int i = tid; i < H2c; i += 128) As[i] = Ap[(size_t)bs * H2c + i] + bL[i];
    __syncthreads();
    int t = tid;
    float m3 = mask[bs] * mask[b * Ln + t];
    float outv[NLABc];
    if (m3 > 0.f) {
        float4 acc[NLABc];
#pragma unroll
        for (int k = 0; k < NLABc; k++) acc[k] = make_float4(0.f, 0.f, 0.f, 0.f);
        const float4* B4 = (const float4*)(B2 + (size_t)(b * Ln + t) * H2c);
        const float4* A4 = (const float4*)As;
        for (int q = 0; q < H2c / 4; q++) {
            float4 a = A4[q], bb = B4[q];
            float4 e;
            e.x = fmaxf(a.x + bb.x, 0.f);
            e.y = fmaxf(a.y + bb.y, 0.f);
            e.z = fmaxf(a.z + bb.z, 0.f);
            e.w = fmaxf(a.w + bb.w, 0.f);
#pragma unroll
            for (int k = 0; k < NLABc; k++) {
                float4 w = *(const float4*)(WCr + k * H2c + q * 4);
                acc[k].x += e.x * w.x; acc[k].y += e.y * w.y;
                acc[k].z += e.z * w.z; acc[k].w += e.w * w.w;
            }
        }
#pragma unroll
        for (int k = 0; k < NLABc; k++)
            outv[k] = sigf(acc[k].x + acc[k].y + acc[k].z + acc[k].w + bCr[k]);
    } else {
#pragma unroll
        for (int k = 0; k < NLABc; k++) outv[k] = 0.f;
    }
    size_t base = ((size_t)bs * Ln + t) * NLABc;
#pragma unroll
    for (int k = 0; k < NLABc; k++) outCr[base + k] = outv[k];
}

// ---------------- GRU pointwise ----------------
__global__ void k_gru_pw(const float* __restrict__ gi, const float* __restrict__ gh,
                         const float* __restrict__ hprev, float* __restrict__ hout) {
    int i = blockIdx.x * 256 + threadIdx.x;
    if (i >= Bn * Ln * H2c) return;
    int m = i / H2c, j = i - m * H2c;
    const float* gim = gi + (size_t)m * G3;
    const float* ghm = gh + (size_t)m * G3;
    float r = sigf(gim[j] + ghm[j]);
    float z = sigf(gim[H2c + j] + ghm[H2c + j]);
    float n = tanhf(gim[2 * H2c + j] + r * ghm[2 * H2c + j]);
    hout[i] = (1.f - z) * n + z * hprev[i];
}

// ---------------- Hc = a + b + c ----------------
__global__ void k_add3(const float* __restrict__ a, const float* __restrict__ b,
                       const float* __restrict__ c, float* __restrict__ o) {
    int i = blockIdx.x * 256 + threadIdx.x;
    if (i >= Bn * Ln * H2c) return;
    o[i] = a[i] + b[i] + c[i];
}

extern "C" void kernel_launch(void* const* d_in, const int* in_sizes, int n_in,
                              void* d_out, int out_size, void* d_ws, size_t ws_size,
                              hipStream_t stream) {
    const int*   tok   = (const int*)d_in[0];
    const int*   pos   = (const int*)d_in[1];
    const float* mask  = (const float*)d_in[2];
    const float* emb   = (const float*)d_in[3];
    const float* pemb  = (const float*)d_in[4];
    const float* WihF  = (const float*)d_in[5];
    const float* WhhF  = (const float*)d_in[6];
    const float* bF    = (const float*)d_in[7];
    const float* WihB  = (const float*)d_in[8];
    const float* WhhB  = (const float*)d_in[9];
    const float* bB    = (const float*)d_in[10];
    const float* Wg_ih = (const float*)d_in[11];
    const float* Wg_hh = (const float*)d_in[12];
    const float* bg_ih = (const float*)d_in[13];
    const float* bg_hh = (const float*)d_in[14];
    const float* Wr_ih = (const float*)d_in[15];
    const float* Wr_hh = (const float*)d_in[16];
    const float* br_ih = (const float*)d_in[17];
    const float* br_hh = (const float*)d_in[18];
    const float* W_Lr  = (const float*)d_in[19];
    const float* b_Lr  = (const float*)d_in[20];
    const float* W_Cr  = (const float*)d_in[21];
    const float* b_Cr  = (const float*)d_in[22];
    const float* W_Cg  = (const float*)d_in[23];
    const float* b_Cg  = (const float*)d_in[24];

    float* outp = (float*)d_out;
    float* ws = (float*)d_ws;
    size_t off = 0;
    auto alloc = [&](size_t n) { float* p = ws + off; off += n; return p; };

    float* x    = alloc((size_t)Bn * Ln * INc);       // 337920
    float* XG   = alloc((size_t)Bn * Ln * G3 * 2);    // shared region: Xpre pair OR gi/gh pair
    float* XpreF = XG;
    float* XpreB = XG + (size_t)Bn * Ln * G4;
    float* gi    = XG;                                // reused after LSTM consumes Xpre
    float* gh    = XG + (size_t)Bn * Ln * G3;
    float* Henc = alloc((size_t)Bn * Ln * H2c);
    float* Hg   = alloc((size_t)Bn * Ln * H2c);
    float* Hr   = alloc((size_t)Bn * Ln * H2c);
    float* Hcb  = alloc((size_t)Bn * Ln * H2c);
    float* Apair  = alloc((size_t)Bn * Ln * H2c);
    float* B2pair = alloc((size_t)Bn * Ln * H2c);
    float* cg   = alloc((size_t)Bn * Ln * NBIOc);
    float* pCg  = alloc((size_t)Bn * Ln * NBIOc);
    float* pCr  = alloc((size_t)Bn * Ln * NLABc);
    (void)ws_size; (void)in_sizes; (void)n_in; (void)out_size;

    auto gemm = [&](const float* A, int lda, const float* Bm, int ldb,
                    const float* bias, float* C, int M, int N, int K) {
        dim3 g((N + 63) / 64, (M + 63) / 64);
        k_gemm_bt<<<g, 256, 0, stream>>>(A, lda, Bm, ldb, bias, C, M, N, K);
    };

    // --- embedding + input projections ---
    k_embed<<<(Bn * Ln * INc + 255) / 256, 256, 0, stream>>>(tok, pos, emb, pemb, x);
    gemm(x, INc, WihF, INc, bF, XpreF, Bn * Ln, G4, INc);
    gemm(x, INc, WihB, INc, bB, XpreB, Bn * Ln, G4, INc);

    // --- bidirectional LSTM ---
    k_lstm<<<16, 1024, 0, stream>>>(XpreF, XpreB, WhhF, WhhB, mask, Henc);

    // --- message-passing rounds ---
    const float* Hgs = Henc;
    const float* Hrs = Henc;
    const float* Hcs = Henc;
    for (int r = 0; r < 2; r++) {
        gemm(Hgs, H2c, W_Cg, H2c, b_Cg, cg, Bn * Ln, NBIOc, H2c);
        k_softmax9<<<4, 256, 0, stream>>>(cg, pCg);

        gemm(Hrs, H2c, W_Lr, 2 * H2c, nullptr, Apair, Bn * Ln, H2c, H2c);
        gemm(Hrs, H2c, W_Lr + H2c, 2 * H2c, nullptr, B2pair, Bn * Ln, H2c, H2c);
        k_pairmax<<<Bn * Ln, 128, 0, stream>>>(Apair, B2pair, b_Lr, W_Cr, b_Cr, mask, pCr);

        gemm(pCg, NBIOc, Wg_ih, NBIOc, bg_ih, gi, Bn * Ln, G3, NBIOc);
        gemm(Hcs, H2c, Wg_hh, H2c, bg_hh, gh, Bn * Ln, G3, H2c);
        k_gru_pw<<<(Bn * Ln * H2c + 255) / 256, 256, 0, stream>>>(gi, gh, Hcs, Hg);

        gemm(pCr, NLABc, Wr_ih, NLABc, br_ih, gi, Bn * Ln, G3, NLABc);
        gemm(Hcs, H2c, Wr_hh, H2c, br_hh, gh, Bn * Ln, G3, H2c);
        k_gru_pw<<<(Bn * Ln * H2c + 255) / 256, 256, 0, stream>>>(gi, gh, Hcs, Hr);

        k_add3<<<(Bn * Ln * H2c + 255) / 256, 256, 0, stream>>>(Hcs, Hr, Hg, Hcb);
        Hgs = Hg; Hrs = Hr; Hcs = Hcb;
    }

    // --- final outputs ---
    gemm(Hgs, H2c, W_Cg, H2c, b_Cg, cg, Bn * Ln, NBIOc, H2c);
    k_logsoftmax9<<<4, 256, 0, stream>>>(cg, mask, outp);

    gemm(Hrs, H2c, W_Lr, 2 * H2c, nullptr, Apair, Bn * Ln, H2c, H2c);
    gemm(Hrs, H2c, W_Lr + H2c, 2 * H2c, nullptr, B2pair, Bn * Ln, H2c, H2c);
    k_pairfull<<<Bn * Ln, 128, 0, stream>>>(Apair, B2pair, b_Lr, W_Cr, b_Cr, mask,
                                            outp + Bn * Ln * NBIOc);
}

// Round 2
// 2070.930 us; speedup vs baseline: 2.3576x; 2.3576x over previous
//
#include <hip/hip_runtime.h>
#include <hip/hip_bf16.h>
#include <stdint.h>

#define DEVI __device__ __forceinline__

static constexpr int Bn = 8, Ln = 128;
static constexpr int EMBc = 300, POSc = 30, INc = 330;
static constexpr int Hc = 256, H2c = 512, G4 = 1024, G3 = 1536;
static constexpr int NBIOc = 9, NLABc = 10;
static constexpr float NEGc = -100000000000.0f;

typedef __attribute__((ext_vector_type(8))) short bf16x8;
typedef __attribute__((ext_vector_type(4))) float f32x4;

DEVI float sigf(float x) { return 1.0f / (1.0f + __expf(-x)); }

DEVI unsigned short b16rne(float f) {
    union { float f; unsigned u; } v; v.f = f;
    unsigned u = v.u;
    return (unsigned short)((u + 0x7FFFu + ((u >> 16) & 1u)) >> 16);
}

// ---------------- embedding: x = concat(emb[tokens], pos_emb[pos]) ----------------
__global__ void k_embed(const int* __restrict__ tok, const int* __restrict__ pos,
                        const float* __restrict__ emb, const float* __restrict__ pemb,
                        float* __restrict__ x) {
    int i = blockIdx.x * 256 + threadIdx.x;
    if (i >= Bn * Ln * INc) return;
    int bl = i / INc, c = i - bl * INc;
    float v;
    if (c < EMBc) v = emb[tok[bl] * EMBc + c];
    else          v = pemb[pos[bl] * POSc + (c - EMBc)];
    x[i] = v;
}

// ---------------- generic C[M,N] = A[M,K](lda) @ B[N,K](ldb)^T + bias ----------------
__global__ __launch_bounds__(256) void k_gemm_bt(
    const float* __restrict__ A, int lda, const float* __restrict__ Bm, int ldb,
    const float* __restrict__ bias, float* __restrict__ C, int M, int N, int K) {
    __shared__ float As[64][17];
    __shared__ float Bs[64][17];
    int tid = threadIdx.x;
    int tx = tid & 15, ty = tid >> 4;
    int m0 = blockIdx.y * 64, n0 = blockIdx.x * 64;
    float acc[4][4] = {};
    for (int k0 = 0; k0 < K; k0 += 16) {
#pragma unroll
        for (int i = 0; i < 4; i++) {
            int idx = tid + i * 256;
            int r = idx >> 4, c = idx & 15;
            int mm = m0 + r, kk = k0 + c;
            As[r][c] = (mm < M && kk < K) ? A[(size_t)mm * lda + kk] : 0.f;
            int nn = n0 + r;
            Bs[r][c] = (nn < N && kk < K) ? Bm[(size_t)nn * ldb + kk] : 0.f;
        }
        __syncthreads();
#pragma unroll
        for (int kk = 0; kk < 16; kk++) {
            float a[4], bb[4];
#pragma unroll
            for (int i = 0; i < 4; i++) { a[i] = As[ty * 4 + i][kk]; bb[i] = Bs[tx * 4 + i][kk]; }
#pragma unroll
            for (int i = 0; i < 4; i++)
#pragma unroll
                for (int j = 0; j < 4; j++) acc[i][j] += a[i] * bb[j];
        }
        __syncthreads();
    }
#pragma unroll
    for (int i = 0; i < 4; i++) {
        int mm = m0 + ty * 4 + i;
        if (mm >= M) continue;
#pragma unroll
        for (int j = 0; j < 4; j++) {
            int nn = n0 + tx * 4 + j;
            if (nn < N) C[(size_t)mm * N + nn] = acc[i][j] + (bias ? bias[nn] : 0.f);
        }
    }
}

// ---------------- bidirectional masked LSTM: MFMA + register-resident weights ----------------
// grid = 8 blocks: block = d*4+q. Block (d,q) owns h-slice [q*64,(q+1)*64) of direction d,
// i.e. weight rows {g*256 + q*64 + jj : g in 0..3, jj in 0..63} (256 rows x 256 k, bf16 in VGPRs).
// Per step: exchange packed-bf16 h via global (double-buffered) + release/acquire flags.
// 512 threads = 8 waves; wave w owns j-tiles {2w, 2w+1}; MFMA 16x16x32 bf16, N=batch(8, padded 16).
__global__ __launch_bounds__(512) void k_lstm_mfma(
    const float* __restrict__ XpreF, const float* __restrict__ XpreB,
    const float* __restrict__ WhhF, const float* __restrict__ WhhB,
    const float* __restrict__ mask, float* __restrict__ Henc,
    uint32_t* __restrict__ hG, int* __restrict__ flag) {
    const int blk = blockIdx.x;
    const int d = blk >> 2, q = blk & 3;
    const float* Xpre = d ? XpreB : XpreF;
    const float* Whh  = d ? WhhB : WhhF;

    const int tid  = threadIdx.x;
    const int lane = tid & 63, wv = tid >> 6;
    const int lr16 = lane & 15, g4 = lane >> 4;   // A row-in-tile, k-group

    __shared__ float Glds[256][9];

    // ---- load A fragments (weights) into registers, fp32 -> bf16 RNE ----
    bf16x8 aw[16];
#pragma unroll
    for (int jt2 = 0; jt2 < 2; jt2++) {
        int jt = wv * 2 + jt2;
        int lr = jt * 16 + lr16;            // local row 0..255
        int g = lr >> 6, jj = lr & 63;
        int R = g * 256 + q * 64 + jj;      // global gate row
        const float* wr = Whh + (size_t)R * 256;
#pragma unroll
        for (int kt = 0; kt < 8; kt++) {
            int k0 = kt * 32 + g4 * 8;
            float4 f0 = *(const float4*)(wr + k0);
            float4 f1 = *(const float4*)(wr + k0 + 4);
            bf16x8 a;
            a[0] = (short)b16rne(f0.x); a[1] = (short)b16rne(f0.y);
            a[2] = (short)b16rne(f0.z); a[3] = (short)b16rne(f0.w);
            a[4] = (short)b16rne(f1.x); a[5] = (short)b16rne(f1.y);
            a[6] = (short)b16rne(f1.z); a[7] = (short)b16rne(f1.w);
            aw[jt2 * 8 + kt] = a;
        }
    }

    // ---- per-thread recurrent state: thread (jj = tid&63, b = tid>>6) ----
    const int jj_t = tid & 63, b_t = tid >> 6;
    float hval = 0.f, cval = 0.f;
    const int bcol = lane & 15;
    const int bb = lane & 7;

    for (int s = 0; s < Ln; s++) {
        const int t = d ? (Ln - 1 - s) : s;

        // issue Xpre gate loads early (independent of partners)
        const float* xrow = Xpre + ((size_t)(b_t * Ln + t)) * G4 + q * 64 + jj_t;
        float xg0 = xrow[0], xg1 = xrow[256], xg2 = xrow[512], xg3 = xrow[768];
        float mval = mask[b_t * Ln + t];

        // wait for partners to have produced h for step s
        if (tid == 0) {
#pragma unroll
            for (int r = 0; r < 4; r++) {
                if (r == q) continue;
                while (__hip_atomic_load(&flag[d * 4 + r], __ATOMIC_ACQUIRE,
                                         __HIP_MEMORY_SCOPE_AGENT) < s) {}
            }
        }
        __syncthreads();

        // ---- load B fragments (h, packed bf16) from exchange buffer ----
        const uint32_t* hGd = hG + (size_t)((s & 1) * 2 + d) * 8 * 128;
        bf16x8 bv[8];
#pragma unroll
        for (int kt = 0; kt < 8; kt++) {
            int kp0 = kt * 16 + g4 * 4;
            uint4 u = *(const uint4*)(hGd + bb * 128 + kp0);
            bv[kt] = *reinterpret_cast<bf16x8*>(&u);
        }

        // ---- MFMA: gates(256 local rows) x batches ----
        f32x4 acc0 = {0.f, 0.f, 0.f, 0.f}, acc1 = {0.f, 0.f, 0.f, 0.f};
#pragma unroll
        for (int kt = 0; kt < 8; kt++) {
            acc0 = __builtin_amdgcn_mfma_f32_16x16x32_bf16(aw[kt], bv[kt], acc0, 0, 0, 0);
            acc1 = __builtin_amdgcn_mfma_f32_16x16x32_bf16(aw[8 + kt], bv[kt], acc1, 0, 0, 0);
        }

        // ---- D -> LDS (only valid batch cols) ----
        if (bcol < 8) {
            int lrb0 = (wv * 2 + 0) * 16 + g4 * 4;
            int lrb1 = (wv * 2 + 1) * 16 + g4 * 4;
#pragma unroll
            for (int r2 = 0; r2 < 4; r2++) Glds[lrb0 + r2][bcol] = acc0[r2];
#pragma unroll
            for (int r2 = 0; r2 < 4; r2++) Glds[lrb1 + r2][bcol] = acc1[r2];
        }
        __syncthreads();

        // ---- pointwise LSTM cell for (jj_t, b_t) ----
        {
            float iv = sigf(xg0 + Glds[jj_t][b_t]);
            float fv = sigf(xg1 + Glds[64 + jj_t][b_t]);
            float gv = tanhf(xg2 + Glds[128 + jj_t][b_t]);
            float ov = sigf(xg3 + Glds[192 + jj_t][b_t]);
            float cn = fv * cval + iv * gv;
            float hn = ov * tanhf(cn);
            float hv = mval * hn + (1.f - mval) * hval;
            cval = mval * cn + (1.f - mval) * cval;
            hval = hv;
            Henc[((size_t)(b_t * Ln + t)) * H2c + d * Hc + q * 64 + jj_t] = hv * mval;

            // pack pair (even jj holds [jj], [jj+1]) as bf16 and publish for step s+1
            int hbits = (int)b16rne(hv);
            int pbits = __shfl_xor(hbits, 1);
            if ((jj_t & 1) == 0) {
                uint32_t u = ((uint32_t)hbits & 0xFFFFu) | ((uint32_t)pbits << 16);
                hG[(size_t)(((s + 1) & 1) * 2 + d) * 8 * 128 + b_t * 128 + q * 32 + (jj_t >> 1)] = u;
            }
        }
        __threadfence();
        __syncthreads();
        if (tid == 0)
            __hip_atomic_store(&flag[d * 4 + q], s + 1, __ATOMIC_RELEASE,
                               __HIP_MEMORY_SCOPE_AGENT);
    }
}

// ---------------- softmax over 9 classes, per row ----------------
__global__ void k_softmax9(const float* __restrict__ lg, float* __restrict__ pr) {
    int r = blockIdx.x * 256 + threadIdx.x;
    if (r >= Bn * Ln) return;
    float v[NBIOc], mx = -3.4e38f;
#pragma unroll
    for (int k = 0; k < NBIOc; k++) { v[k] = lg[r * NBIOc + k]; mx = fmaxf(mx, v[k]); }
    float s = 0.f;
#pragma unroll
    for (int k = 0; k < NBIOc; k++) { v[k] = __expf(v[k] - mx); s += v[k]; }
    float inv = 1.f / s;
#pragma unroll
    for (int k = 0; k < NBIOc; k++) pr[r * NBIOc + k] = v[k] * inv;
}

// ---------------- log_softmax over 9 classes * mask, per row ----------------
__global__ void k_logsoftmax9(const float* __restrict__ lg, const float* __restrict__ mask,
                              float* __restrict__ outp) {
    int r = blockIdx.x * 256 + threadIdx.x;
    if (r >= Bn * Ln) return;
    float v[NBIOc], mx = -3.4e38f;
#pragma unroll
    for (int k = 0; k < NBIOc; k++) { v[k] = lg[r * NBIOc + k]; mx = fmaxf(mx, v[k]); }
    float s = 0.f;
#pragma unroll
    for (int k = 0; k < NBIOc; k++) s += __expf(v[k] - mx);
    float lse = mx + __logf(s);
    float m = mask[r];
#pragma unroll
    for (int k = 0; k < NBIOc; k++) outp[r * NBIOc + k] = (v[k] - lse) * m;
}

// ---------------- pair scores with masked max over t ----------------
__global__ __launch_bounds__(128) void k_pairmax(
    const float* __restrict__ Ap, const float* __restrict__ B2,
    const float* __restrict__ bL, const float* __restrict__ WCr,
    const float* __restrict__ bCr, const float* __restrict__ mask,
    float* __restrict__ probCr) {
    int bs = blockIdx.x;
    int b = bs >> 7;
    __shared__ __align__(16) float As[H2c];
    __shared__ float red[NLABc][128];
    int tid = threadIdx.x;
    for (int i = tid; i < H2c; i += 128) As[i] = Ap[(size_t)bs * H2c + i] + bL[i];
    __syncthreads();
    int t = tid;
    float m3 = mask[bs] * mask[b * Ln + t];
    float outv[NLABc];
    if (m3 > 0.f) {
        float4 acc[NLABc];
#pragma unroll
        for (int k = 0; k < NLABc; k++) acc[k] = make_float4(0.f, 0.f, 0.f, 0.f);
        const float4* B4 = (const float4*)(B2 + (size_t)(b * Ln + t) * H2c);
        const float4* A4 = (const float4*)As;
        for (int q = 0; q < H2c / 4; q++) {
            float4 a = A4[q], bb = B4[q];
            float4 e;
            e.x = fmaxf(a.x + bb.x, 0.f);
            e.y = fmaxf(a.y + bb.y, 0.f);
            e.z = fmaxf(a.z + bb.z, 0.f);
            e.w = fmaxf(a.w + bb.w, 0.f);
#pragma unroll
            for (int k = 0; k < NLABc; k++) {
                float4 w = *(const float4*)(WCr + k * H2c + q * 4);
                acc[k].x += e.x * w.x; acc[k].y += e.y * w.y;
                acc[k].z += e.z * w.z; acc[k].w += e.w * w.w;
            }
        }
#pragma unroll
        for (int k = 0; k < NLABc; k++)
            outv[k] = sigf(acc[k].x + acc[k].y + acc[k].z + acc[k].w + bCr[k]);
    } else {
#pragma unroll
        for (int k = 0; k < NLABc; k++) outv[k] = NEGc;
    }
#pragma unroll
    for (int k = 0; k < NLABc; k++) red[k][tid] = outv[k];
    __syncthreads();
    for (int off = 64; off >= 1; off >>= 1) {
        if (tid < off) {
#pragma unroll
            for (int k = 0; k < NLABc; k++) red[k][tid] = fmaxf(red[k][tid], red[k][tid + off]);
        }
        __syncthreads();
    }
    if (tid < NLABc) probCr[bs * NLABc + tid] = red[tid][0];
}

// ---------------- full pair scores * m3 (final output) ----------------
__global__ __launch_bounds__(128) void k_pairfull(
    const float* __restrict__ Ap, const float* __restrict__ B2,
    const float* __restrict__ bL, const float* __restrict__ WCr,
    const float* __restrict__ bCr, const float* __restrict__ mask,
    float* __restrict__ outCr) {
    int bs = blockIdx.x;
    int b = bs >> 7;
    __shared__ __align__(16) float As[H2c];
    int tid = threadIdx.x;
    for (int i = tid; i < H2c; i += 128) As[i] = Ap[(size_t)bs * H2c + i] + bL[i];
    __syncthreads();
    int t = tid;
    float m3 = mask[bs] * mask[b * Ln + t];
    float outv[NLABc];
    if (m3 > 0.f) {
        float4 acc[NLABc];
#pragma unroll
        for (int k = 0; k < NLABc; k++) acc[k] = make_float4(0.f, 0.f, 0.f, 0.f);
        const float4* B4 = (const float4*)(B2 + (size_t)(b * Ln + t) * H2c);
        const float4* A4 = (const float4*)As;
        for (int q = 0; q < H2c / 4; q++) {
            float4 a = A4[q], bb = B4[q];
            float4 e;
            e.x = fmaxf(a.x + bb.x, 0.f);
            e.y = fmaxf(a.y + bb.y, 0.f);
            e.z = fmaxf(a.z + bb.z, 0.f);
            e.w = fmaxf(a.w + bb.w, 0.f);
#pragma unroll
            for (int k = 0; k < NLABc; k++) {
                float4 w = *(const float4*)(WCr + k * H2c + q * 4);
                acc[k].x += e.x * w.x; acc[k].y += e.y * w.y;
                acc[k].z += e.z * w.z; acc[k].w += e.w * w.w;
            }
        }
#pragma unroll
        for (int k = 0; k < NLABc; k++)
            outv[k] = sigf(acc[k].x + acc[k].y + acc[k].z + acc[k].w + bCr[k]);
    } else {
#pragma unroll
        for (int k = 0; k < NLABc; k++) outv[k] = 0.f;
    }
    size_t base = ((size_t)bs * Ln + t) * NLABc;
#pragma unroll
    for (int k = 0; k < NLABc; k++) outCr[base + k] = outv[k];
}

// ---------------- GRU pointwise ----------------
__global__ void k_gru_pw(const float* __restrict__ gi, const float* __restrict__ gh,
                         const float* __restrict__ hprev, float* __restrict__ hout) {
    int i = blockIdx.x * 256 + threadIdx.x;
    if (i >= Bn * Ln * H2c) return;
    int m = i / H2c, j = i - m * H2c;
    const float* gim = gi + (size_t)m * G3;
    const float* ghm = gh + (size_t)m * G3;
    float r = sigf(gim[j] + ghm[j]);
    float z = sigf(gim[H2c + j] + ghm[H2c + j]);
    float n = tanhf(gim[2 * H2c + j] + r * ghm[2 * H2c + j]);
    hout[i] = (1.f - z) * n + z * hprev[i];
}

// ---------------- Hc = a + b + c ----------------
__global__ void k_add3(const float* __restrict__ a, const float* __restrict__ b,
                       const float* __restrict__ c, float* __restrict__ o) {
    int i = blockIdx.x * 256 + threadIdx.x;
    if (i >= Bn * Ln * H2c) return;
    o[i] = a[i] + b[i] + c[i];
}

extern "C" void kernel_launch(void* const* d_in, const int* in_sizes, int n_in,
                              void* d_out, int out_size, void* d_ws, size_t ws_size,
                              hipStream_t stream) {
    const int*   tok   = (const int*)d_in[0];
    const int*   pos   = (const int*)d_in[1];
    const float* mask  = (const float*)d_in[2];
    const float* emb   = (const float*)d_in[3];
    const float* pemb  = (const float*)d_in[4];
    const float* WihF  = (const float*)d_in[5];
    const float* WhhF  = (const float*)d_in[6];
    const float* bF    = (const float*)d_in[7];
    const float* WihB  = (const float*)d_in[8];
    const float* WhhB  = (const float*)d_in[9];
    const float* bB    = (const float*)d_in[10];
    const float* Wg_ih = (const float*)d_in[11];
    const float* Wg_hh = (const float*)d_in[12];
    const float* bg_ih = (const float*)d_in[13];
    const float* bg_hh = (const float*)d_in[14];
    const float* Wr_ih = (const float*)d_in[15];
    const float* Wr_hh = (const float*)d_in[16];
    const float* br_ih = (const float*)d_in[17];
    const float* br_hh = (const float*)d_in[18];
    const float* W_Lr  = (const float*)d_in[19];
    const float* b_Lr  = (const float*)d_in[20];
    const float* W_Cr  = (const float*)d_in[21];
    const float* b_Cr  = (const float*)d_in[22];
    const float* W_Cg  = (const float*)d_in[23];
    const float* b_Cg  = (const float*)d_in[24];

    float* outp = (float*)d_out;
    float* ws = (float*)d_ws;

    // sync region first: flags[16] + hG[2][2][8][128] u32, memset to 0 each call
    uint32_t* syncb = (uint32_t*)ws;
    int*      flag  = (int*)syncb;
    uint32_t* hG    = syncb + 16;
    const size_t SYNC_WORDS = 16 + 2 * 2 * 8 * 128;   // 4112 -> round to 4352

    size_t off = 4352;
    auto alloc = [&](size_t n) { float* p = ws + off; off += n; return p; };

    float* x    = alloc((size_t)Bn * Ln * INc);
    float* XG   = alloc((size_t)Bn * Ln * G3 * 2);
    float* XpreF = XG;
    float* XpreB = XG + (size_t)Bn * Ln * G4;
    float* gi    = XG;
    float* gh    = XG + (size_t)Bn * Ln * G3;
    float* Henc = alloc((size_t)Bn * Ln * H2c);
    float* Hg   = alloc((size_t)Bn * Ln * H2c);
    float* Hr   = alloc((size_t)Bn * Ln * H2c);
    float* Hcb  = alloc((size_t)Bn * Ln * H2c);
    float* Apair  = alloc((size_t)Bn * Ln * H2c);
    float* B2pair = alloc((size_t)Bn * Ln * H2c);
    float* cg   = alloc((size_t)Bn * Ln * NBIOc);
    float* pCg  = alloc((size_t)Bn * Ln * NBIOc);
    float* pCr  = alloc((size_t)Bn * Ln * NLABc);
    (void)ws_size; (void)in_sizes; (void)n_in; (void)out_size;

    auto gemm = [&](const float* A, int lda, const float* Bm, int ldb,
                    const float* bias, float* C, int M, int N, int K) {
        dim3 g((N + 63) / 64, (M + 63) / 64);
        k_gemm_bt<<<g, 256, 0, stream>>>(A, lda, Bm, ldb, bias, C, M, N, K);
    };

    // --- reset sync region (stream-ordered before LSTM) ---
    hipMemsetAsync(syncb, 0, SYNC_WORDS * sizeof(uint32_t), stream);

    // --- embedding + input projections ---
    k_embed<<<(Bn * Ln * INc + 255) / 256, 256, 0, stream>>>(tok, pos, emb, pemb, x);
    gemm(x, INc, WihF, INc, bF, XpreF, Bn * Ln, G4, INc);
    gemm(x, INc, WihB, INc, bB, XpreB, Bn * Ln, G4, INc);

    // --- bidirectional LSTM (8 co-resident blocks, cross-block h exchange) ---
    k_lstm_mfma<<<8, 512, 0, stream>>>(XpreF, XpreB, WhhF, WhhB, mask, Henc, hG, flag);

    // --- message-passing rounds ---
    const float* Hgs = Henc;
    const float* Hrs = Henc;
    const float* Hcs = Henc;
    for (int r = 0; r < 2; r++) {
        gemm(Hgs, H2c, W_Cg, H2c, b_Cg, cg, Bn * Ln, NBIOc, H2c);
        k_softmax9<<<4, 256, 0, stream>>>(cg, pCg);

        gemm(Hrs, H2c, W_Lr, 2 * H2c, nullptr, Apair, Bn * Ln, H2c, H2c);
        gemm(Hrs, H2c, W_Lr + H2c, 2 * H2c, nullptr, B2pair, Bn * Ln, H2c, H2c);
        k_pairmax<<<Bn * Ln, 128, 0, stream>>>(Apair, B2pair, b_Lr, W_Cr, b_Cr, mask, pCr);

        gemm(pCg, NBIOc, Wg_ih, NBIOc, bg_ih, gi, Bn * Ln, G3, NBIOc);
        gemm(Hcs, H2c, Wg_hh, H2c, bg_hh, gh, Bn * Ln, G3, H2c);
        k_gru_pw<<<(Bn * Ln * H2c + 255) / 256, 256, 0, stream>>>(gi, gh, Hcs, Hg);

        gemm(pCr, NLABc, Wr_ih, NLABc, br_ih, gi, Bn * Ln, G3, NLABc);
        gemm(Hcs, H2c, Wr_hh, H2c, br_hh, gh, Bn * Ln, G3, H2c);
        k_gru_pw<<<(Bn * Ln * H2c + 255) / 256, 256, 0, stream>>>(gi, gh, Hcs, Hr);

        k_add3<<<(Bn * Ln * H2c + 255) / 256, 256, 0, stream>>>(Hcs, Hr, Hg, Hcb);
        Hgs = Hg; Hrs = Hr; Hcs = Hcb;
    }

    // --- final outputs ---
    gemm(Hgs, H2c, W_Cg, H2c, b_Cg, cg, Bn * Ln, NBIOc, H2c);
    k_logsoftmax9<<<4, 256, 0, stream>>>(cg, mask, outp);

    gemm(Hrs, H2c, W_Lr, 2 * H2c, nullptr, Apair, Bn * Ln, H2c, H2c);
    gemm(Hrs, H2c, W_Lr + H2c, 2 * H2c, nullptr, B2pair, Bn * Ln, H2c, H2c);
    k_pairfull<<<Bn * Ln, 128, 0, stream>>>(Apair, B2pair, b_Lr, W_Cr, b_Cr, mask,
                                            outp + Bn * Ln * NBIOc);
}

// Round 3
// 1882.380 us; speedup vs baseline: 2.5937x; 1.1002x over previous
//
#include <hip/hip_runtime.h>
#include <hip/hip_bf16.h>
#include <stdint.h>

#define DEVI __device__ __forceinline__

static constexpr int Bn = 8, Ln = 128;
static constexpr int EMBc = 300, POSc = 30, INc = 330;
static constexpr int Hc = 256, H2c = 512, G4 = 1024, G3 = 1536;
static constexpr int NBIOc = 9, NLABc = 10;
static constexpr float NEGc = -100000000000.0f;

typedef __attribute__((ext_vector_type(8))) short bf16x8;
typedef __attribute__((ext_vector_type(4))) float f32x4;

DEVI float sigf(float x) { return 1.0f / (1.0f + __expf(-x)); }

DEVI unsigned short b16rne(float f) {
    union { float f; unsigned u; } v; v.f = f;
    unsigned u = v.u;
    return (unsigned short)((u + 0x7FFFu + ((u >> 16) & 1u)) >> 16);
}

DEVI uint32_t ag_load(const uint32_t* p) {
    return __hip_atomic_load(p, __ATOMIC_RELAXED, __HIP_MEMORY_SCOPE_AGENT);
}
DEVI void ag_store(uint32_t* p, uint32_t v) {
    __hip_atomic_store(p, v, __ATOMIC_RELAXED, __HIP_MEMORY_SCOPE_AGENT);
}
DEVI int ag_load_i(const int* p) {
    return __hip_atomic_load(p, __ATOMIC_RELAXED, __HIP_MEMORY_SCOPE_AGENT);
}
DEVI void ag_store_i(int* p, int v) {
    __hip_atomic_store(p, v, __ATOMIC_RELAXED, __HIP_MEMORY_SCOPE_AGENT);
}

// ---------------- embedding: x = concat(emb[tokens], pos_emb[pos]) ----------------
__global__ void k_embed(const int* __restrict__ tok, const int* __restrict__ pos,
                        const float* __restrict__ emb, const float* __restrict__ pemb,
                        float* __restrict__ x) {
    int i = blockIdx.x * 256 + threadIdx.x;
    if (i >= Bn * Ln * INc) return;
    int bl = i / INc, c = i - bl * INc;
    float v;
    if (c < EMBc) v = emb[tok[bl] * EMBc + c];
    else          v = pemb[pos[bl] * POSc + (c - EMBc)];
    x[i] = v;
}

// ---------------- generic C[M,N] = A[M,K](lda) @ B[N,K](ldb)^T + bias ----------------
__global__ __launch_bounds__(256) void k_gemm_bt(
    const float* __restrict__ A, int lda, const float* __restrict__ Bm, int ldb,
    const float* __restrict__ bias, float* __restrict__ C, int M, int N, int K) {
    __shared__ float As[64][17];
    __shared__ float Bs[64][17];
    int tid = threadIdx.x;
    int tx = tid & 15, ty = tid >> 4;
    int m0 = blockIdx.y * 64, n0 = blockIdx.x * 64;
    float acc[4][4] = {};
    for (int k0 = 0; k0 < K; k0 += 16) {
#pragma unroll
        for (int i = 0; i < 4; i++) {
            int idx = tid + i * 256;
            int r = idx >> 4, c = idx & 15;
            int mm = m0 + r, kk = k0 + c;
            As[r][c] = (mm < M && kk < K) ? A[(size_t)mm * lda + kk] : 0.f;
            int nn = n0 + r;
            Bs[r][c] = (nn < N && kk < K) ? Bm[(size_t)nn * ldb + kk] : 0.f;
        }
        __syncthreads();
#pragma unroll
        for (int kk = 0; kk < 16; kk++) {
            float a[4], bb[4];
#pragma unroll
            for (int i = 0; i < 4; i++) { a[i] = As[ty * 4 + i][kk]; bb[i] = Bs[tx * 4 + i][kk]; }
#pragma unroll
            for (int i = 0; i < 4; i++)
#pragma unroll
                for (int j = 0; j < 4; j++) acc[i][j] += a[i] * bb[j];
        }
        __syncthreads();
    }
#pragma unroll
    for (int i = 0; i < 4; i++) {
        int mm = m0 + ty * 4 + i;
        if (mm >= M) continue;
#pragma unroll
        for (int j = 0; j < 4; j++) {
            int nn = n0 + tx * 4 + j;
            if (nn < N) C[(size_t)mm * N + nn] = acc[i][j] + (bias ? bias[nn] : 0.f);
        }
    }
}

// ---------------- bidirectional masked LSTM: MFMA + register-resident weights ----------------
// 8 blocks (d*4+q), 512 threads. Weights (256 rows x 256 k, bf16) in VGPRs.
// Cross-block h exchange via relaxed agent-scope atomics (coherence-point read/write,
// no buffer_inv/wbl2); flags padded 128B; 3 partner flags polled in parallel.
__global__ __launch_bounds__(512) void k_lstm_mfma(
    const float* __restrict__ XpreF, const float* __restrict__ XpreB,
    const float* __restrict__ WhhF, const float* __restrict__ WhhB,
    const float* __restrict__ mask, float* __restrict__ Henc,
    uint32_t* __restrict__ hG, int* __restrict__ flag) {
    const int blk = blockIdx.x;
    const int d = blk >> 2, q = blk & 3;
    const float* Xpre = d ? XpreB : XpreF;
    const float* Whh  = d ? WhhB : WhhF;

    const int tid  = threadIdx.x;
    const int lane = tid & 63, wv = tid >> 6;
    const int lr16 = lane & 15, g4 = lane >> 4;

    __shared__ float Glds[256][9];

    // ---- load A fragments (weights) into registers, fp32 -> bf16 RNE ----
    bf16x8 aw[16];
#pragma unroll
    for (int jt2 = 0; jt2 < 2; jt2++) {
        int jt = wv * 2 + jt2;
        int lr = jt * 16 + lr16;
        int g = lr >> 6, jj = lr & 63;
        int R = g * 256 + q * 64 + jj;
        const float* wr = Whh + (size_t)R * 256;
#pragma unroll
        for (int kt = 0; kt < 8; kt++) {
            int k0 = kt * 32 + g4 * 8;
            float4 f0 = *(const float4*)(wr + k0);
            float4 f1 = *(const float4*)(wr + k0 + 4);
            bf16x8 a;
            a[0] = (short)b16rne(f0.x); a[1] = (short)b16rne(f0.y);
            a[2] = (short)b16rne(f0.z); a[3] = (short)b16rne(f0.w);
            a[4] = (short)b16rne(f1.x); a[5] = (short)b16rne(f1.y);
            a[6] = (short)b16rne(f1.z); a[7] = (short)b16rne(f1.w);
            aw[jt2 * 8 + kt] = a;
        }
    }

    const int jj_t = tid & 63, b_t = tid >> 6;
    float hval = 0.f, cval = 0.f;
    const int bcol = lane & 15;
    const int bb = lane & 7;

    for (int s = 0; s < Ln; s++) {
        const int t = d ? (Ln - 1 - s) : s;

        const float* xrow = Xpre + ((size_t)(b_t * Ln + t)) * G4 + q * 64 + jj_t;
        float xg0 = xrow[0], xg1 = xrow[256], xg2 = xrow[512], xg3 = xrow[768];
        float mval = mask[b_t * Ln + t];

        // wait for the 3 partners (parallel pollers, relaxed agent loads)
        if (tid < 4 && tid != q) {
            while (ag_load_i(&flag[(d * 4 + tid) * 32]) < s) {}
        }
        __syncthreads();

        // ---- load B fragments (h, packed bf16) from coherence point ----
        const uint32_t* hGd = hG + (size_t)((s & 1) * 2 + d) * 8 * 128;
        bf16x8 bv[8];
#pragma unroll
        for (int kt = 0; kt < 8; kt++) {
            int kp0 = kt * 16 + g4 * 4;
            uint32_t tmp[4];
            tmp[0] = ag_load(hGd + bb * 128 + kp0 + 0);
            tmp[1] = ag_load(hGd + bb * 128 + kp0 + 1);
            tmp[2] = ag_load(hGd + bb * 128 + kp0 + 2);
            tmp[3] = ag_load(hGd + bb * 128 + kp0 + 3);
            bv[kt] = *reinterpret_cast<bf16x8*>(tmp);
        }

        // ---- MFMA ----
        f32x4 acc0 = {0.f, 0.f, 0.f, 0.f}, acc1 = {0.f, 0.f, 0.f, 0.f};
#pragma unroll
        for (int kt = 0; kt < 8; kt++) {
            acc0 = __builtin_amdgcn_mfma_f32_16x16x32_bf16(aw[kt], bv[kt], acc0, 0, 0, 0);
            acc1 = __builtin_amdgcn_mfma_f32_16x16x32_bf16(aw[8 + kt], bv[kt], acc1, 0, 0, 0);
        }

        // ---- D -> LDS ----
        if (bcol < 8) {
            int lrb0 = (wv * 2 + 0) * 16 + g4 * 4;
            int lrb1 = (wv * 2 + 1) * 16 + g4 * 4;
#pragma unroll
            for (int r2 = 0; r2 < 4; r2++) Glds[lrb0 + r2][bcol] = acc0[r2];
#pragma unroll
            for (int r2 = 0; r2 < 4; r2++) Glds[lrb1 + r2][bcol] = acc1[r2];
        }
        __syncthreads();

        // ---- pointwise LSTM cell ----
        {
            float iv = sigf(xg0 + Glds[jj_t][b_t]);
            float fv = sigf(xg1 + Glds[64 + jj_t][b_t]);
            float gv = tanhf(xg2 + Glds[128 + jj_t][b_t]);
            float ov = sigf(xg3 + Glds[192 + jj_t][b_t]);
            float cn = fv * cval + iv * gv;
            float hn = ov * tanhf(cn);
            float hv = mval * hn + (1.f - mval) * hval;
            cval = mval * cn + (1.f - mval) * cval;
            hval = hv;
            Henc[((size_t)(b_t * Ln + t)) * H2c + d * Hc + q * 64 + jj_t] = hv * mval;

            int hbits = (int)b16rne(hv);
            int pbits = __shfl_xor(hbits, 1);
            if ((jj_t & 1) == 0) {
                uint32_t u = ((uint32_t)hbits & 0xFFFFu) | ((uint32_t)pbits << 16);
                ag_store(hG + (size_t)(((s + 1) & 1) * 2 + d) * 8 * 128 +
                             b_t * 128 + q * 32 + (jj_t >> 1), u);
            }
        }
        // per-wave drain of the agent-scope data stores, then block-wide join
        asm volatile("s_waitcnt vmcnt(0)" ::: "memory");
        __syncthreads();
        if (tid == 0) ag_store_i(&flag[(d * 4 + q) * 32], s + 1);
    }
}

// ---------------- softmax over 9 classes, per row ----------------
__global__ void k_softmax9(const float* __restrict__ lg, float* __restrict__ pr) {
    int r = blockIdx.x * 256 + threadIdx.x;
    if (r >= Bn * Ln) return;
    float v[NBIOc], mx = -3.4e38f;
#pragma unroll
    for (int k = 0; k < NBIOc; k++) { v[k] = lg[r * NBIOc + k]; mx = fmaxf(mx, v[k]); }
    float s = 0.f;
#pragma unroll
    for (int k = 0; k < NBIOc; k++) { v[k] = __expf(v[k] - mx); s += v[k]; }
    float inv = 1.f / s;
#pragma unroll
    for (int k = 0; k < NBIOc; k++) pr[r * NBIOc + k] = v[k] * inv;
}

// ---------------- log_softmax over 9 classes * mask, per row ----------------
__global__ void k_logsoftmax9(const float* __restrict__ lg, const float* __restrict__ mask,
                              float* __restrict__ outp) {
    int r = blockIdx.x * 256 + threadIdx.x;
    if (r >= Bn * Ln) return;
    float v[NBIOc], mx = -3.4e38f;
#pragma unroll
    for (int k = 0; k < NBIOc; k++) { v[k] = lg[r * NBIOc + k]; mx = fmaxf(mx, v[k]); }
    float s = 0.f;
#pragma unroll
    for (int k = 0; k < NBIOc; k++) s += __expf(v[k] - mx);
    float lse = mx + __logf(s);
    float m = mask[r];
#pragma unroll
    for (int k = 0; k < NBIOc; k++) outp[r * NBIOc + k] = (v[k] - lse) * m;
}

// ---------------- pair scores with masked max over t (WCr staged in LDS) ----------------
__global__ __launch_bounds__(128) void k_pairmax(
    const float* __restrict__ Ap, const float* __restrict__ B2,
    const float* __restrict__ bL, const float* __restrict__ WCr,
    const float* __restrict__ bCr, const float* __restrict__ mask,
    float* __restrict__ probCr) {
    int bs = blockIdx.x;
    int b = bs >> 7;
    __shared__ __align__(16) float As[H2c];
    __shared__ __align__(16) float Ws[NLABc][H2c];
    __shared__ float red[NLABc][128];
    int tid = threadIdx.x;
    for (int i = tid; i < H2c; i += 128) As[i] = Ap[(size_t)bs * H2c + i] + bL[i];
    for (int i = tid; i < NLABc * H2c; i += 128) Ws[i / H2c][i % H2c] = WCr[i];
    __syncthreads();
    int t = tid;
    float m3 = mask[bs] * mask[b * Ln + t];
    float outv[NLABc];
    if (m3 > 0.f) {
        float4 acc[NLABc];
#pragma unroll
        for (int k = 0; k < NLABc; k++) acc[k] = make_float4(0.f, 0.f, 0.f, 0.f);
        const float4* B4 = (const float4*)(B2 + (size_t)(b * Ln + t) * H2c);
        const float4* A4 = (const float4*)As;
        for (int q = 0; q < H2c / 4; q++) {
            float4 a = A4[q], bb = B4[q];
            float4 e;
            e.x = fmaxf(a.x + bb.x, 0.f);
            e.y = fmaxf(a.y + bb.y, 0.f);
            e.z = fmaxf(a.z + bb.z, 0.f);
            e.w = fmaxf(a.w + bb.w, 0.f);
#pragma unroll
            for (int k = 0; k < NLABc; k++) {
                float4 w = *(const float4*)(&Ws[k][q * 4]);
                acc[k].x += e.x * w.x; acc[k].y += e.y * w.y;
                acc[k].z += e.z * w.z; acc[k].w += e.w * w.w;
            }
        }
#pragma unroll
        for (int k = 0; k < NLABc; k++)
            outv[k] = sigf(acc[k].x + acc[k].y + acc[k].z + acc[k].w + bCr[k]);
    } else {
#pragma unroll
        for (int k = 0; k < NLABc; k++) outv[k] = NEGc;
    }
#pragma unroll
    for (int k = 0; k < NLABc; k++) red[k][tid] = outv[k];
    __syncthreads();
    for (int off = 64; off >= 1; off >>= 1) {
        if (tid < off) {
#pragma unroll
            for (int k = 0; k < NLABc; k++) red[k][tid] = fmaxf(red[k][tid], red[k][tid + off]);
        }
        __syncthreads();
    }
    if (tid < NLABc) probCr[bs * NLABc + tid] = red[tid][0];
}

// ---------------- full pair scores * m3 (final output, WCr staged in LDS) ----------------
__global__ __launch_bounds__(128) void k_pairfull(
    const float* __restrict__ Ap, const float* __restrict__ B2,
    const float* __restrict__ bL, const float* __restrict__ WCr,
    const float* __restrict__ bCr, const float* __restrict__ mask,
    float* __restrict__ outCr) {
    int bs = blockIdx.x;
    int b = bs >> 7;
    __shared__ __align__(16) float As[H2c];
    __shared__ __align__(16) float Ws[NLABc][H2c];
    int tid = threadIdx.x;
    for (int i = tid; i < H2c; i += 128) As[i] = Ap[(size_t)bs * H2c + i] + bL[i];
    for (int i = tid; i < NLABc * H2c; i += 128) Ws[i / H2c][i % H2c] = WCr[i];
    __syncthreads();
    int t = tid;
    float m3 = mask[bs] * mask[b * Ln + t];
    float outv[NLABc];
    if (m3 > 0.f) {
        float4 acc[NLABc];
#pragma unroll
        for (int k = 0; k < NLABc; k++) acc[k] = make_float4(0.f, 0.f, 0.f, 0.f);
        const float4* B4 = (const float4*)(B2 + (size_t)(b * Ln + t) * H2c);
        const float4* A4 = (const float4*)As;
        for (int q = 0; q < H2c / 4; q++) {
            float4 a = A4[q], bb = B4[q];
            float4 e;
            e.x = fmaxf(a.x + bb.x, 0.f);
            e.y = fmaxf(a.y + bb.y, 0.f);
            e.z = fmaxf(a.z + bb.z, 0.f);
            e.w = fmaxf(a.w + bb.w, 0.f);
#pragma unroll
            for (int k = 0; k < NLABc; k++) {
                float4 w = *(const float4*)(&Ws[k][q * 4]);
                acc[k].x += e.x * w.x; acc[k].y += e.y * w.y;
                acc[k].z += e.z * w.z; acc[k].w += e.w * w.w;
            }
        }
#pragma unroll
        for (int k = 0; k < NLABc; k++)
            outv[k] = sigf(acc[k].x + acc[k].y + acc[k].z + acc[k].w + bCr[k]);
    } else {
#pragma unroll
        for (int k = 0; k < NLABc; k++) outv[k] = 0.f;
    }
    size_t base = ((size_t)bs * Ln + t) * NLABc;
#pragma unroll
    for (int k = 0; k < NLABc; k++) outCr[base + k] = outv[k];
}

// ---------------- GRU pointwise ----------------
__global__ void k_gru_pw(const float* __restrict__ gi, const float* __restrict__ gh,
                         const float* __restrict__ hprev, float* __restrict__ hout) {
    int i = blockIdx.x * 256 + threadIdx.x;
    if (i >= Bn * Ln * H2c) return;
    int m = i / H2c, j = i - m * H2c;
    const float* gim = gi + (size_t)m * G3;
    const float* ghm = gh + (size_t)m * G3;
    float r = sigf(gim[j] + ghm[j]);
    float z = sigf(gim[H2c + j] + ghm[H2c + j]);
    float n = tanhf(gim[2 * H2c + j] + r * ghm[2 * H2c + j]);
    hout[i] = (1.f - z) * n + z * hprev[i];
}

// ---------------- GRU pointwise + fused Hc = hprev + hr + Hg ----------------
__global__ void k_gru_pw2(const float* __restrict__ gi, const float* __restrict__ gh,
                          const float* __restrict__ hprev, const float* __restrict__ Hgv,
                          float* __restrict__ hr_out, float* __restrict__ hc_out) {
    int i = blockIdx.x * 256 + threadIdx.x;
    if (i >= Bn * Ln * H2c) return;
    int m = i / H2c, j = i - m * H2c;
    const float* gim = gi + (size_t)m * G3;
    const float* ghm = gh + (size_t)m * G3;
    float r = sigf(gim[j] + ghm[j]);
    float z = sigf(gim[H2c + j] + ghm[H2c + j]);
    float n = tanhf(gim[2 * H2c + j] + r * ghm[2 * H2c + j]);
    float hp = hprev[i];
    float hr = (1.f - z) * n + z * hp;
    hr_out[i] = hr;
    hc_out[i] = hp + hr + Hgv[i];
}

extern "C" void kernel_launch(void* const* d_in, const int* in_sizes, int n_in,
                              void* d_out, int out_size, void* d_ws, size_t ws_size,
                              hipStream_t stream) {
    const int*   tok   = (const int*)d_in[0];
    const int*   pos   = (const int*)d_in[1];
    const float* mask  = (const float*)d_in[2];
    const float* emb   = (const float*)d_in[3];
    const float* pemb  = (const float*)d_in[4];
    const float* WihF  = (const float*)d_in[5];
    const float* WhhF  = (const float*)d_in[6];
    const float* bF    = (const float*)d_in[7];
    const float* WihB  = (const float*)d_in[8];
    const float* WhhB  = (const float*)d_in[9];
    const float* bB    = (const float*)d_in[10];
    const float* Wg_ih = (const float*)d_in[11];
    const float* Wg_hh = (const float*)d_in[12];
    const float* bg_ih = (const float*)d_in[13];
    const float* bg_hh = (const float*)d_in[14];
    const float* Wr_ih = (const float*)d_in[15];
    const float* Wr_hh = (const float*)d_in[16];
    const float* br_ih = (const float*)d_in[17];
    const float* br_hh = (const float*)d_in[18];
    const float* W_Lr  = (const float*)d_in[19];
    const float* b_Lr  = (const float*)d_in[20];
    const float* W_Cr  = (const float*)d_in[21];
    const float* b_Cr  = (const float*)d_in[22];
    const float* W_Cg  = (const float*)d_in[23];
    const float* b_Cg  = (const float*)d_in[24];

    float* outp = (float*)d_out;
    float* ws = (float*)d_ws;

    // sync region: 16 flags x 32 ints (128B apart) + hG[2][2][8][128] u32
    uint32_t* syncb = (uint32_t*)ws;
    int*      flag  = (int*)syncb;
    uint32_t* hG    = syncb + 512;
    const size_t SYNC_WORDS = 512 + 2 * 2 * 8 * 128;   // 4608

    size_t off = 4608;
    auto alloc = [&](size_t n) { float* p = ws + off; off += n; return p; };

    float* x    = alloc((size_t)Bn * Ln * INc);
    float* XG   = alloc((size_t)Bn * Ln * G3 * 2);
    float* XpreF = XG;
    float* XpreB = XG + (size_t)Bn * Ln * G4;
    float* gi    = XG;
    float* gh    = XG + (size_t)Bn * Ln * G3;
    float* Henc = alloc((size_t)Bn * Ln * H2c);
    float* Hg   = alloc((size_t)Bn * Ln * H2c);
    float* Hr   = alloc((size_t)Bn * Ln * H2c);
    float* Hcb  = alloc((size_t)Bn * Ln * H2c);
    float* Apair  = alloc((size_t)Bn * Ln * H2c);
    float* B2pair = alloc((size_t)Bn * Ln * H2c);
    float* cg   = alloc((size_t)Bn * Ln * NBIOc);
    float* pCg  = alloc((size_t)Bn * Ln * NBIOc);
    float* pCr  = alloc((size_t)Bn * Ln * NLABc);
    (void)ws_size; (void)in_sizes; (void)n_in; (void)out_size;

    auto gemm = [&](const float* A, int lda, const float* Bm, int ldb,
                    const float* bias, float* C, int M, int N, int K) {
        dim3 g((N + 63) / 64, (M + 63) / 64);
        k_gemm_bt<<<g, 256, 0, stream>>>(A, lda, Bm, ldb, bias, C, M, N, K);
    };

    // --- reset sync region (stream-ordered before LSTM) ---
    hipMemsetAsync(syncb, 0, SYNC_WORDS * sizeof(uint32_t), stream);

    // --- embedding + input projections ---
    k_embed<<<(Bn * Ln * INc + 255) / 256, 256, 0, stream>>>(tok, pos, emb, pemb, x);
    gemm(x, INc, WihF, INc, bF, XpreF, Bn * Ln, G4, INc);
    gemm(x, INc, WihB, INc, bB, XpreB, Bn * Ln, G4, INc);

    // --- bidirectional LSTM ---
    k_lstm_mfma<<<8, 512, 0, stream>>>(XpreF, XpreB, WhhF, WhhB, mask, Henc, hG, flag);

    // --- message-passing rounds ---
    const float* Hgs = Henc;
    const float* Hrs = Henc;
    const float* Hcs = Henc;
    for (int r = 0; r < 2; r++) {
        gemm(Hgs, H2c, W_Cg, H2c, b_Cg, cg, Bn * Ln, NBIOc, H2c);
        k_softmax9<<<4, 256, 0, stream>>>(cg, pCg);

        gemm(Hrs, H2c, W_Lr, 2 * H2c, nullptr, Apair, Bn * Ln, H2c, H2c);
        gemm(Hrs, H2c, W_Lr + H2c, 2 * H2c, nullptr, B2pair, Bn * Ln, H2c, H2c);
        k_pairmax<<<Bn * Ln, 128, 0, stream>>>(Apair, B2pair, b_Lr, W_Cr, b_Cr, mask, pCr);

        gemm(pCg, NBIOc, Wg_ih, NBIOc, bg_ih, gi, Bn * Ln, G3, NBIOc);
        gemm(Hcs, H2c, Wg_hh, H2c, bg_hh, gh, Bn * Ln, G3, H2c);
        k_gru_pw<<<(Bn * Ln * H2c + 255) / 256, 256, 0, stream>>>(gi, gh, Hcs, Hg);

        gemm(pCr, NLABc, Wr_ih, NLABc, br_ih, gi, Bn * Ln, G3, NLABc);
        gemm(Hcs, H2c, Wr_hh, H2c, br_hh, gh, Bn * Ln, G3, H2c);
        k_gru_pw2<<<(Bn * Ln * H2c + 255) / 256, 256, 0, stream>>>(gi, gh, Hcs, Hg, Hr, Hcb);

        Hgs = Hg; Hrs = Hr; Hcs = Hcb;
    }

    // --- final outputs ---
    gemm(Hgs, H2c, W_Cg, H2c, b_Cg, cg, Bn * Ln, NBIOc, H2c);
    k_logsoftmax9<<<4, 256, 0, stream>>>(cg, mask, outp);

    gemm(Hrs, H2c, W_Lr, 2 * H2c, nullptr, Apair, Bn * Ln, H2c, H2c);
    gemm(Hrs, H2c, W_Lr + H2c, 2 * H2c, nullptr, B2pair, Bn * Ln, H2c, H2c);
    k_pairfull<<<Bn * Ln, 128, 0, stream>>>(Apair, B2pair, b_Lr, W_Cr, b_Cr, mask,
                                            outp + Bn * Ln * NBIOc);
}

// Round 4
// 777.427 us; speedup vs baseline: 6.2802x; 2.4213x over previous
//
#include <hip/hip_runtime.h>
#include <hip/hip_bf16.h>
#include <stdint.h>

#define DEVI __device__ __forceinline__

static constexpr int Bn = 8, Ln = 128;
static constexpr int EMBc = 300, POSc = 30, INc = 330;
static constexpr int KPAD = 384;                   // padded K for input projection
static constexpr int Hc = 256, H2c = 512, G4 = 1024, G3 = 1536;
static constexpr int NBIOc = 9, NLABc = 10;
static constexpr float NEGc = -100000000000.0f;

typedef __attribute__((ext_vector_type(8))) short bf16x8;
typedef __attribute__((ext_vector_type(4))) float f32x4;

DEVI float sigf(float x) { return 1.0f / (1.0f + __expf(-x)); }

DEVI unsigned short b16rne(float f) {
    union { float f; unsigned u; } v; v.f = f;
    unsigned u = v.u;
    return (unsigned short)((u + 0x7FFFu + ((u >> 16) & 1u)) >> 16);
}

// ---------------- embedding -> bf16 padded x [1024][384] ----------------
__global__ void k_embed_bf(const int* __restrict__ tok, const int* __restrict__ pos,
                           const float* __restrict__ emb, const float* __restrict__ pemb,
                           ushort* __restrict__ x) {
    int i = blockIdx.x * 256 + threadIdx.x;
    if (i >= Bn * Ln * KPAD) return;
    int bl = i / KPAD, c = i - bl * KPAD;
    float v = 0.f;
    if (c < EMBc) v = emb[tok[bl] * EMBc + c];
    else if (c < INc) v = pemb[pos[bl] * POSc + (c - EMBc)];
    x[i] = b16rne(v);
}

// ---------------- fp32 -> bf16 (with optional column pad) ----------------
__global__ void k_f2b(const float* __restrict__ src, int src_ld, int cols, int pad_ld,
                      ushort* __restrict__ dst, int total) {
    int i = blockIdx.x * 256 + threadIdx.x;
    if (i >= total) return;
    int r = i / pad_ld, c = i - r * pad_ld;
    float v = (c < cols) ? src[(size_t)r * src_ld + c] : 0.f;
    dst[i] = b16rne(v);
}

// ---------------- MFMA bf16 GEMM: C[M,N] = A[M,K] @ B[N,K]^T + bias ----------------
// M,N multiples of 64; K multiple of 64. 64x64 tile, 4 waves (2x2 of 32x32).
__global__ __launch_bounds__(256) void k_gemm_bf(
    const ushort* __restrict__ A, const ushort* __restrict__ B,
    const float* __restrict__ bias, float* __restrict__ C, int M, int N, int K) {
    __shared__ __align__(16) ushort As[64][72];   // 144B row stride (9x16B)
    __shared__ __align__(16) ushort Bs[64][72];
    int tid = threadIdx.x;
    int lane = tid & 63, wv = tid >> 6;
    int m0 = blockIdx.y * 64, n0 = blockIdx.x * 64;
    int mw = (wv >> 1) * 32, nw = (wv & 1) * 32;
    int lr16 = lane & 15, g4 = lane >> 4;
    f32x4 acc[2][2] = {};
    for (int k0 = 0; k0 < K; k0 += 64) {
#pragma unroll
        for (int it = 0; it < 2; it++) {
            int idx = tid + it * 256;
            int r = idx >> 3, ch = idx & 7;
            uint4 av = *(const uint4*)(A + (size_t)(m0 + r) * K + k0 + ch * 8);
            *(uint4*)(&As[r][ch * 8]) = av;
            uint4 bv2 = *(const uint4*)(B + (size_t)(n0 + r) * K + k0 + ch * 8);
            *(uint4*)(&Bs[r][ch * 8]) = bv2;
        }
        __syncthreads();
#pragma unroll
        for (int ks = 0; ks < 2; ks++) {
            bf16x8 af[2], bfr[2];
#pragma unroll
            for (int i = 0; i < 2; i++) {
                af[i]  = *(const bf16x8*)(&As[mw + i * 16 + lr16][ks * 32 + g4 * 8]);
                bfr[i] = *(const bf16x8*)(&Bs[nw + i * 16 + lr16][ks * 32 + g4 * 8]);
            }
#pragma unroll
            for (int i = 0; i < 2; i++)
#pragma unroll
                for (int j = 0; j < 2; j++)
                    acc[i][j] = __builtin_amdgcn_mfma_f32_16x16x32_bf16(af[i], bfr[j], acc[i][j], 0, 0, 0);
        }
        __syncthreads();
    }
#pragma unroll
    for (int i = 0; i < 2; i++)
#pragma unroll
        for (int j = 0; j < 2; j++)
#pragma unroll
            for (int r2 = 0; r2 < 4; r2++) {
                int mm = m0 + mw + i * 16 + g4 * 4 + r2;
                int nn = n0 + nw + j * 16 + lr16;
                C[(size_t)mm * N + nn] = acc[i][j][r2] + (bias ? bias[nn] : 0.f);
            }
}

// ---------------- fp32 GEMM (kept for the small N=9 projections) ----------------
__global__ __launch_bounds__(256) void k_gemm_bt(
    const float* __restrict__ A, int lda, const float* __restrict__ Bm, int ldb,
    const float* __restrict__ bias, float* __restrict__ C, int M, int N, int K) {
    __shared__ float As[64][17];
    __shared__ float Bs[64][17];
    int tid = threadIdx.x;
    int tx = tid & 15, ty = tid >> 4;
    int m0 = blockIdx.y * 64, n0 = blockIdx.x * 64;
    float acc[4][4] = {};
    for (int k0 = 0; k0 < K; k0 += 16) {
#pragma unroll
        for (int i = 0; i < 4; i++) {
            int idx = tid + i * 256;
            int r = idx >> 4, c = idx & 15;
            int mm = m0 + r, kk = k0 + c;
            As[r][c] = (mm < M && kk < K) ? A[(size_t)mm * lda + kk] : 0.f;
            int nn = n0 + r;
            Bs[r][c] = (nn < N && kk < K) ? Bm[(size_t)nn * ldb + kk] : 0.f;
        }
        __syncthreads();
#pragma unroll
        for (int kk = 0; kk < 16; kk++) {
            float a[4], bb[4];
#pragma unroll
            for (int i = 0; i < 4; i++) { a[i] = As[ty * 4 + i][kk]; bb[i] = Bs[tx * 4 + i][kk]; }
#pragma unroll
            for (int i = 0; i < 4; i++)
#pragma unroll
                for (int j = 0; j < 4; j++) acc[i][j] += a[i] * bb[j];
        }
        __syncthreads();
    }
#pragma unroll
    for (int i = 0; i < 4; i++) {
        int mm = m0 + ty * 4 + i;
        if (mm >= M) continue;
#pragma unroll
        for (int j = 0; j < 4; j++) {
            int nn = n0 + tx * 4 + j;
            if (nn < N) C[(size_t)mm * N + nn] = acc[i][j] + (bias ? bias[nn] : 0.f);
        }
    }
}

// ---------------- bidirectional masked LSTM: MFMA, tag-embedded h exchange ----------------
// 8 blocks (d*4+q), 512 threads. Weight slice (256 rows x 256 k, bf16) in VGPRs.
// h exchanged as u64 words {data: 2xbf16, tag: step} via agent-scope atomics;
// consumers poll the data words directly (no flags, no producer drain).
// hG layout: [slot(2)][dir(2)][1024 u64], unit u = b*128 + q*32 + pairidx.
__global__ __launch_bounds__(512) void k_lstm_mfma(
    const float* __restrict__ XpreF, const float* __restrict__ XpreB,
    const float* __restrict__ WhhF, const float* __restrict__ WhhB,
    const float* __restrict__ mask, float* __restrict__ Henc,
    ushort* __restrict__ HencB, unsigned long long* __restrict__ hG) {
    const int blk = blockIdx.x;
    const int d = blk >> 2, q = blk & 3;
    const float* Xpre = d ? XpreB : XpreF;
    const float* Whh  = d ? WhhB : WhhF;

    const int tid  = threadIdx.x;
    const int lane = tid & 63, wv = tid >> 6;
    const int lr16 = lane & 15, g4 = lane >> 4;

    __shared__ __align__(16) uint32_t hlds[8 * 132];   // b rows, stride 132 u32
    __shared__ float Glds[256][9];

    // ---- weights -> registers (fp32 -> bf16 RNE) ----
    bf16x8 aw[16];
#pragma unroll
    for (int jt2 = 0; jt2 < 2; jt2++) {
        int jt = wv * 2 + jt2;
        int lr = jt * 16 + lr16;
        int g = lr >> 6, jj = lr & 63;
        int R = g * 256 + q * 64 + jj;
        const float* wr = Whh + (size_t)R * 256;
#pragma unroll
        for (int kt = 0; kt < 8; kt++) {
            int k0 = kt * 32 + g4 * 8;
            float4 f0 = *(const float4*)(wr + k0);
            float4 f1 = *(const float4*)(wr + k0 + 4);
            bf16x8 a;
            a[0] = (short)b16rne(f0.x); a[1] = (short)b16rne(f0.y);
            a[2] = (short)b16rne(f0.z); a[3] = (short)b16rne(f0.w);
            a[4] = (short)b16rne(f1.x); a[5] = (short)b16rne(f1.y);
            a[6] = (short)b16rne(f1.z); a[7] = (short)b16rne(f1.w);
            aw[jt2 * 8 + kt] = a;
        }
    }

    const int jj_t = tid & 63, b_t = tid >> 6;
    float hval = 0.f, cval = 0.f;
    const int bcol = lane & 15;
    const int bb = lane & 7;
    const int u1 = tid + 512;

    for (int s = 0; s < Ln; s++) {
        const int t = d ? (Ln - 1 - s) : s;

        const float* xrow = Xpre + ((size_t)(b_t * Ln + t)) * G4 + q * 64 + jj_t;
        float xg0 = xrow[0], xg1 = xrow[256], xg2 = xrow[512], xg3 = xrow[768];
        float mval = mask[b_t * Ln + t];

        // ---- poll 2 tagged u64 units (tag == s); memset(0) covers s=0 (h0 = 0) ----
        const unsigned long long* slot = hG + ((size_t)(s & 1) * 2 + d) * 1024;
        unsigned long long ea, eb;
        do {
            ea = __hip_atomic_load(slot + tid, __ATOMIC_RELAXED, __HIP_MEMORY_SCOPE_AGENT);
            eb = __hip_atomic_load(slot + u1,  __ATOMIC_RELAXED, __HIP_MEMORY_SCOPE_AGENT);
        } while ((unsigned)(ea >> 32) != (unsigned)s || (unsigned)(eb >> 32) != (unsigned)s);
        hlds[(tid >> 7) * 132 + (tid & 127)] = (uint32_t)ea;
        hlds[(u1 >> 7) * 132 + (u1 & 127)]  = (uint32_t)eb;
        __syncthreads();

        // ---- B fragments from LDS ----
        bf16x8 bv[8];
#pragma unroll
        for (int kt = 0; kt < 8; kt++)
            bv[kt] = *(const bf16x8*)(&hlds[bb * 132 + kt * 16 + g4 * 4]);

        // ---- MFMA ----
        f32x4 acc0 = {0.f, 0.f, 0.f, 0.f}, acc1 = {0.f, 0.f, 0.f, 0.f};
#pragma unroll
        for (int kt = 0; kt < 8; kt++) {
            acc0 = __builtin_amdgcn_mfma_f32_16x16x32_bf16(aw[kt], bv[kt], acc0, 0, 0, 0);
            acc1 = __builtin_amdgcn_mfma_f32_16x16x32_bf16(aw[8 + kt], bv[kt], acc1, 0, 0, 0);
        }

        // ---- D -> LDS ----
        if (bcol < 8) {
            int lrb0 = (wv * 2 + 0) * 16 + g4 * 4;
            int lrb1 = (wv * 2 + 1) * 16 + g4 * 4;
#pragma unroll
            for (int r2 = 0; r2 < 4; r2++) Glds[lrb0 + r2][bcol] = acc0[r2];
#pragma unroll
            for (int r2 = 0; r2 < 4; r2++) Glds[lrb1 + r2][bcol] = acc1[r2];
        }
        __syncthreads();

        // ---- pointwise LSTM cell ----
        float iv = sigf(xg0 + Glds[jj_t][b_t]);
        float fv = sigf(xg1 + Glds[64 + jj_t][b_t]);
        float gv = tanhf(xg2 + Glds[128 + jj_t][b_t]);
        float ov = sigf(xg3 + Glds[192 + jj_t][b_t]);
        float cn = fv * cval + iv * gv;
        float hn = ov * tanhf(cn);
        float hv = mval * hn + (1.f - mval) * hval;
        cval = mval * cn + (1.f - mval) * cval;
        hval = hv;
        float ho = hv * mval;
        size_t hidx = ((size_t)(b_t * Ln + t)) * H2c + d * Hc + q * 64 + jj_t;
        Henc[hidx] = ho;
        HencB[hidx] = b16rne(ho);

        // ---- publish h for step s+1 as tagged u64 ----
        int hbits = (int)b16rne(hv);
        int pbits = __shfl_xor(hbits, 1);
        if ((jj_t & 1) == 0) {
            uint32_t dataw = ((uint32_t)hbits & 0xFFFFu) | ((uint32_t)pbits << 16);
            unsigned long long word = ((unsigned long long)(unsigned)(s + 1) << 32) | dataw;
            __hip_atomic_store(hG + ((size_t)((s + 1) & 1) * 2 + d) * 1024 +
                                   b_t * 128 + q * 32 + (jj_t >> 1),
                               word, __ATOMIC_RELAXED, __HIP_MEMORY_SCOPE_AGENT);
        }
        __syncthreads();   // keep waves in step (barrier before next poll/overwrite)
    }
}

// ---------------- softmax over 9 classes ----------------
__global__ void k_softmax9(const float* __restrict__ lg, float* __restrict__ pr) {
    int r = blockIdx.x * 256 + threadIdx.x;
    if (r >= Bn * Ln) return;
    float v[NBIOc], mx = -3.4e38f;
#pragma unroll
    for (int k = 0; k < NBIOc; k++) { v[k] = lg[r * NBIOc + k]; mx = fmaxf(mx, v[k]); }
    float s = 0.f;
#pragma unroll
    for (int k = 0; k < NBIOc; k++) { v[k] = __expf(v[k] - mx); s += v[k]; }
    float inv = 1.f / s;
#pragma unroll
    for (int k = 0; k < NBIOc; k++) pr[r * NBIOc + k] = v[k] * inv;
}

// ---------------- log_softmax * mask ----------------
__global__ void k_logsoftmax9(const float* __restrict__ lg, const float* __restrict__ mask,
                              float* __restrict__ outp) {
    int r = blockIdx.x * 256 + threadIdx.x;
    if (r >= Bn * Ln) return;
    float v[NBIOc], mx = -3.4e38f;
#pragma unroll
    for (int k = 0; k < NBIOc; k++) { v[k] = lg[r * NBIOc + k]; mx = fmaxf(mx, v[k]); }
    float s = 0.f;
#pragma unroll
    for (int k = 0; k < NBIOc; k++) s += __expf(v[k] - mx);
    float lse = mx + __logf(s);
    float m = mask[r];
#pragma unroll
    for (int k = 0; k < NBIOc; k++) outp[r * NBIOc + k] = (v[k] - lse) * m;
}

// ---------------- pair scores with masked max over t ----------------
__global__ __launch_bounds__(128) void k_pairmax(
    const float* __restrict__ Ap, const float* __restrict__ B2,
    const float* __restrict__ bL, const float* __restrict__ WCr,
    const float* __restrict__ bCr, const float* __restrict__ mask,
    float* __restrict__ probCr) {
    int bs = blockIdx.x;
    int b = bs >> 7;
    __shared__ __align__(16) float As[H2c];
    __shared__ __align__(16) float Ws[NLABc][H2c];
    __shared__ float red[NLABc][128];
    int tid = threadIdx.x;
    for (int i = tid; i < H2c; i += 128) As[i] = Ap[(size_t)bs * H2c + i] + bL[i];
    for (int i = tid; i < NLABc * H2c; i += 128) Ws[i / H2c][i % H2c] = WCr[i];
    __syncthreads();
    int t = tid;
    float m3 = mask[bs] * mask[b * Ln + t];
    float outv[NLABc];
    if (m3 > 0.f) {
        float4 acc[NLABc];
#pragma unroll
        for (int k = 0; k < NLABc; k++) acc[k] = make_float4(0.f, 0.f, 0.f, 0.f);
        const float4* B4 = (const float4*)(B2 + (size_t)(b * Ln + t) * H2c);
        const float4* A4 = (const float4*)As;
        for (int qq = 0; qq < H2c / 4; qq++) {
            float4 a = A4[qq], bb = B4[qq];
            float4 e;
            e.x = fmaxf(a.x + bb.x, 0.f);
            e.y = fmaxf(a.y + bb.y, 0.f);
            e.z = fmaxf(a.z + bb.z, 0.f);
            e.w = fmaxf(a.w + bb.w, 0.f);
#pragma unroll
            for (int k = 0; k < NLABc; k++) {
                float4 w = *(const float4*)(&Ws[k][qq * 4]);
                acc[k].x += e.x * w.x; acc[k].y += e.y * w.y;
                acc[k].z += e.z * w.z; acc[k].w += e.w * w.w;
            }
        }
#pragma unroll
        for (int k = 0; k < NLABc; k++)
            outv[k] = sigf(acc[k].x + acc[k].y + acc[k].z + acc[k].w + bCr[k]);
    } else {
#pragma unroll
        for (int k = 0; k < NLABc; k++) outv[k] = NEGc;
    }
#pragma unroll
    for (int k = 0; k < NLABc; k++) red[k][tid] = outv[k];
    __syncthreads();
    for (int off = 64; off >= 1; off >>= 1) {
        if (tid < off) {
#pragma unroll
            for (int k = 0; k < NLABc; k++) red[k][tid] = fmaxf(red[k][tid], red[k][tid + off]);
        }
        __syncthreads();
    }
    if (tid < NLABc) probCr[bs * NLABc + tid] = red[tid][0];
}

// ---------------- full pair scores * m3 (final output) ----------------
__global__ __launch_bounds__(128) void k_pairfull(
    const float* __restrict__ Ap, const float* __restrict__ B2,
    const float* __restrict__ bL, const float* __restrict__ WCr,
    const float* __restrict__ bCr, const float* __restrict__ mask,
    float* __restrict__ outCr) {
    int bs = blockIdx.x;
    int b = bs >> 7;
    __shared__ __align__(16) float As[H2c];
    __shared__ __align__(16) float Ws[NLABc][H2c];
    int tid = threadIdx.x;
    for (int i = tid; i < H2c; i += 128) As[i] = Ap[(size_t)bs * H2c + i] + bL[i];
    for (int i = tid; i < NLABc * H2c; i += 128) Ws[i / H2c][i % H2c] = WCr[i];
    __syncthreads();
    int t = tid;
    float m3 = mask[bs] * mask[b * Ln + t];
    float outv[NLABc];
    if (m3 > 0.f) {
        float4 acc[NLABc];
#pragma unroll
        for (int k = 0; k < NLABc; k++) acc[k] = make_float4(0.f, 0.f, 0.f, 0.f);
        const float4* B4 = (const float4*)(B2 + (size_t)(b * Ln + t) * H2c);
        const float4* A4 = (const float4*)As;
        for (int qq = 0; qq < H2c / 4; qq++) {
            float4 a = A4[qq], bb = B4[qq];
            float4 e;
            e.x = fmaxf(a.x + bb.x, 0.f);
            e.y = fmaxf(a.y + bb.y, 0.f);
            e.z = fmaxf(a.z + bb.z, 0.f);
            e.w = fmaxf(a.w + bb.w, 0.f);
#pragma unroll
            for (int k = 0; k < NLABc; k++) {
                float4 w = *(const float4*)(&Ws[k][qq * 4]);
                acc[k].x += e.x * w.x; acc[k].y += e.y * w.y;
                acc[k].z += e.z * w.z; acc[k].w += e.w * w.w;
            }
        }
#pragma unroll
        for (int k = 0; k < NLABc; k++)
            outv[k] = sigf(acc[k].x + acc[k].y + acc[k].z + acc[k].w + bCr[k]);
    } else {
#pragma unroll
        for (int k = 0; k < NLABc; k++) outv[k] = 0.f;
    }
    size_t base = ((size_t)bs * Ln + t) * NLABc;
#pragma unroll
    for (int k = 0; k < NLABc; k++) outCr[base + k] = outv[k];
}

// ---------------- GRU pointwise with fused ih projection ----------------
__global__ void k_gru_pw(const float* __restrict__ gh, const float* __restrict__ p_in, int PW,
                         const float* __restrict__ W_ih, const float* __restrict__ b_ih,
                         const float* __restrict__ hprev, float* __restrict__ hout) {
    int i = blockIdx.x * 256 + threadIdx.x;
    if (i >= Bn * Ln * H2c) return;
    int m = i / H2c, j = i - m * H2c;
    const float* p = p_in + (size_t)m * PW;
    float gr = b_ih[j], gz = b_ih[H2c + j], gn = b_ih[2 * H2c + j];
    for (int k = 0; k < PW; k++) {
        float pv = p[k];
        gr += W_ih[(size_t)j * PW + k] * pv;
        gz += W_ih[(size_t)(H2c + j) * PW + k] * pv;
        gn += W_ih[(size_t)(2 * H2c + j) * PW + k] * pv;
    }
    const float* ghm = gh + (size_t)m * G3;
    float r = sigf(gr + ghm[j]);
    float z = sigf(gz + ghm[H2c + j]);
    float n = tanhf(gn + r * ghm[2 * H2c + j]);
    hout[i] = (1.f - z) * n + z * hprev[i];
}

// ---------------- GRU pointwise (fused ih) + Hc = hp + hr + Hg, + bf16 outputs ----------------
__global__ void k_gru_pw2(const float* __restrict__ gh, const float* __restrict__ p_in, int PW,
                          const float* __restrict__ W_ih, const float* __restrict__ b_ih,
                          const float* __restrict__ hprev, const float* __restrict__ Hgv,
                          float* __restrict__ hr_out, ushort* __restrict__ hrb_out,
                          float* __restrict__ hc_out, ushort* __restrict__ hcb_out) {
    int i = blockIdx.x * 256 + threadIdx.x;
    if (i >= Bn * Ln * H2c) return;
    int m = i / H2c, j = i - m * H2c;
    const float* p = p_in + (size_t)m * PW;
    float gr = b_ih[j], gz = b_ih[H2c + j], gn = b_ih[2 * H2c + j];
    for (int k = 0; k < PW; k++) {
        float pv = p[k];
        gr += W_ih[(size_t)j * PW + k] * pv;
        gz += W_ih[(size_t)(H2c + j) * PW + k] * pv;
        gn += W_ih[(size_t)(2 * H2c + j) * PW + k] * pv;
    }
    const float* ghm = gh + (size_t)m * G3;
    float r = sigf(gr + ghm[j]);
    float z = sigf(gz + ghm[H2c + j]);
    float n = tanhf(gn + r * ghm[2 * H2c + j]);
    float hp = hprev[i];
    float hr = (1.f - z) * n + z * hp;
    float hc = hp + hr + Hgv[i];
    hr_out[i] = hr;
    hrb_out[i] = b16rne(hr);
    hc_out[i] = hc;
    hcb_out[i] = b16rne(hc);
}

extern "C" void kernel_launch(void* const* d_in, const int* in_sizes, int n_in,
                              void* d_out, int out_size, void* d_ws, size_t ws_size,
                              hipStream_t stream) {
    const int*   tok   = (const int*)d_in[0];
    const int*   pos   = (const int*)d_in[1];
    const float* mask  = (const float*)d_in[2];
    const float* emb   = (const float*)d_in[3];
    const float* pemb  = (const float*)d_in[4];
    const float* WihF  = (const float*)d_in[5];
    const float* WhhF  = (const float*)d_in[6];
    const float* bF    = (const float*)d_in[7];
    const float* WihB  = (const float*)d_in[8];
    const float* WhhB  = (const float*)d_in[9];
    const float* bB    = (const float*)d_in[10];
    const float* Wg_ih = (const float*)d_in[11];
    const float* Wg_hh = (const float*)d_in[12];
    const float* bg_ih = (const float*)d_in[13];
    const float* bg_hh = (const float*)d_in[14];
    const float* Wr_ih = (const float*)d_in[15];
    const float* Wr_hh = (const float*)d_in[16];
    const float* br_ih = (const float*)d_in[17];
    const float* br_hh = (const float*)d_in[18];
    const float* W_Lr  = (const float*)d_in[19];
    const float* b_Lr  = (const float*)d_in[20];
    const float* W_Cr  = (const float*)d_in[21];
    const float* b_Cr  = (const float*)d_in[22];
    const float* W_Cg  = (const float*)d_in[23];
    const float* b_Cg  = (const float*)d_in[24];

    float* outp = (float*)d_out;
    float* ws = (float*)d_ws;

    // sync region: hG[2 slots][2 dir][1024] u64 = 32KB
    unsigned long long* hG = (unsigned long long*)ws;
    const size_t SYNC_FLOATS = 8192;

    size_t off = SYNC_FLOATS;
    auto alloc = [&](size_t n) { float* p = ws + off; off += n; return p; };
    auto allocU = [&](size_t n_us) { ushort* p = (ushort*)(ws + off); off += (n_us + 1) / 2; return p; };

    ushort* x_bf    = allocU((size_t)Bn * Ln * KPAD);
    ushort* WihF_bf = allocU((size_t)G4 * KPAD);
    ushort* WihB_bf = allocU((size_t)G4 * KPAD);
    ushort* Wghh_bf = allocU((size_t)G3 * H2c);
    ushort* Wrhh_bf = allocU((size_t)G3 * H2c);
    ushort* WLrA_bf = allocU((size_t)H2c * H2c);
    ushort* WLrB_bf = allocU((size_t)H2c * H2c);

    // shared region: Xpre pair (8MB) | gh (6MB) | Apair+B2pair (4MB)
    float* XG = alloc((size_t)2 * G4 * G4 / 4 * 4);   // 2*1024*1024 floats
    float* XpreF = XG;
    float* XpreB = XG + (size_t)Bn * Ln * G4;
    float* gh    = XG;
    float* Apair  = XG;
    float* B2pair = XG + (size_t)Bn * Ln * H2c;

    float*  Henc    = alloc((size_t)Bn * Ln * H2c);
    ushort* Henc_bf = allocU((size_t)Bn * Ln * H2c);
    float*  Hg      = alloc((size_t)Bn * Ln * H2c);
    float*  Hr      = alloc((size_t)Bn * Ln * H2c);
    float*  Hcb     = alloc((size_t)Bn * Ln * H2c);
    ushort* Hr_bf   = allocU((size_t)Bn * Ln * H2c);
    ushort* Hcb_bf  = allocU((size_t)Bn * Ln * H2c);
    float*  cg      = alloc((size_t)Bn * Ln * NBIOc);
    float*  pCg     = alloc((size_t)Bn * Ln * NBIOc);
    float*  pCr     = alloc((size_t)Bn * Ln * NLABc);
    (void)ws_size; (void)in_sizes; (void)n_in; (void)out_size;

    auto gemm_bf = [&](const ushort* A, const ushort* B, const float* bias,
                       float* C, int M, int N, int K) {
        dim3 g(N / 64, M / 64);
        k_gemm_bf<<<g, 256, 0, stream>>>(A, B, bias, C, M, N, K);
    };
    auto gemm32 = [&](const float* A, int lda, const float* Bm, int ldb,
                      const float* bias, float* C, int M, int N, int K) {
        dim3 g((N + 63) / 64, (M + 63) / 64);
        k_gemm_bt<<<g, 256, 0, stream>>>(A, lda, Bm, ldb, bias, C, M, N, K);
    };
    auto f2b = [&](const float* src, int src_ld, int cols, int pad_ld, ushort* dst, int rows) {
        int total = rows * pad_ld;
        k_f2b<<<(total + 255) / 256, 256, 0, stream>>>(src, src_ld, cols, pad_ld, dst, total);
    };

    // --- reset exchange buffer (tag 0 == h0 = 0 for step 0) ---
    hipMemsetAsync(hG, 0, SYNC_FLOATS * sizeof(float), stream);

    // --- embed + weight conversions ---
    k_embed_bf<<<(Bn * Ln * KPAD + 255) / 256, 256, 0, stream>>>(tok, pos, emb, pemb, x_bf);
    f2b(WihF, INc, INc, KPAD, WihF_bf, G4);
    f2b(WihB, INc, INc, KPAD, WihB_bf, G4);
    f2b(Wg_hh, H2c, H2c, H2c, Wghh_bf, G3);
    f2b(Wr_hh, H2c, H2c, H2c, Wrhh_bf, G3);
    f2b(W_Lr, 2 * H2c, H2c, H2c, WLrA_bf, H2c);
    f2b(W_Lr + H2c, 2 * H2c, H2c, H2c, WLrB_bf, H2c);

    // --- input projections (MFMA bf16) ---
    gemm_bf(x_bf, WihF_bf, bF, XpreF, Bn * Ln, G4, KPAD);
    gemm_bf(x_bf, WihB_bf, bB, XpreB, Bn * Ln, G4, KPAD);

    // --- bidirectional LSTM ---
    k_lstm_mfma<<<8, 512, 0, stream>>>(XpreF, XpreB, WhhF, WhhB, mask, Henc, Henc_bf, hG);

    // --- message-passing rounds ---
    const float*  Hgs    = Henc;
    const ushort* Hrs_bf = Henc_bf;
    const float*  Hcs    = Henc;
    const ushort* Hcs_bf = Henc_bf;
    for (int r = 0; r < 2; r++) {
        gemm32(Hgs, H2c, W_Cg, H2c, b_Cg, cg, Bn * Ln, NBIOc, H2c);
        k_softmax9<<<4, 256, 0, stream>>>(cg, pCg);

        gemm_bf(Hrs_bf, WLrA_bf, nullptr, Apair, Bn * Ln, H2c, H2c);
        gemm_bf(Hrs_bf, WLrB_bf, nullptr, B2pair, Bn * Ln, H2c, H2c);
        k_pairmax<<<Bn * Ln, 128, 0, stream>>>(Apair, B2pair, b_Lr, W_Cr, b_Cr, mask, pCr);

        gemm_bf(Hcs_bf, Wghh_bf, bg_hh, gh, Bn * Ln, G3, H2c);
        k_gru_pw<<<(Bn * Ln * H2c + 255) / 256, 256, 0, stream>>>(
            gh, pCg, NBIOc, Wg_ih, bg_ih, Hcs, Hg);

        gemm_bf(Hcs_bf, Wrhh_bf, br_hh, gh, Bn * Ln, G3, H2c);
        k_gru_pw2<<<(Bn * Ln * H2c + 255) / 256, 256, 0, stream>>>(
            gh, pCr, NLABc, Wr_ih, br_ih, Hcs, Hg, Hr, Hr_bf, Hcb, Hcb_bf);

        Hgs = Hg; Hrs_bf = Hr_bf; Hcs = Hcb; Hcs_bf = Hcb_bf;
    }

    // --- final outputs ---
    gemm32(Hgs, H2c, W_Cg, H2c, b_Cg, cg, Bn * Ln, NBIOc, H2c);
    k_logsoftmax9<<<4, 256, 0, stream>>>(cg, mask, outp);

    gemm_bf(Hrs_bf, WLrA_bf, nullptr, Apair, Bn * Ln, H2c, H2c);
    gemm_bf(Hrs_bf, WLrB_bf, nullptr, B2pair, Bn * Ln, H2c, H2c);
    k_pairfull<<<Bn * Ln, 128, 0, stream>>>(Apair, B2pair, b_Lr, W_Cr, b_Cr, mask,
                                            outp + Bn * Ln * NBIOc);
}

// Round 5
// 483.175 us; speedup vs baseline: 10.1048x; 1.6090x over previous
//
#include <hip/hip_runtime.h>
#include <hip/hip_bf16.h>
#include <stdint.h>

#define DEVI __device__ __forceinline__

static constexpr int Bn = 8, Ln = 128;
static constexpr int EMBc = 300, POSc = 30, INc = 330;
static constexpr int KPAD = 384;
static constexpr int Hc = 256, H2c = 512, G4 = 1024, G3 = 1536;
static constexpr int G2 = 2048;     // combined F/B gate width
static constexpr int GHW = 3072;    // combined g/r GRU hh width
static constexpr int NBIOc = 9, NLABc = 10;
static constexpr float NEGc = -100000000000.0f;

typedef __attribute__((ext_vector_type(8))) short bf16x8;
typedef __attribute__((ext_vector_type(4))) float f32x4;

DEVI float sigf(float x) { return 1.0f / (1.0f + __expf(-x)); }

DEVI unsigned short b16rne(float f) {
    union { float f; unsigned u; } v; v.f = f;
    unsigned u = v.u;
    return (unsigned short)((u + 0x7FFFu + ((u >> 16) & 1u)) >> 16);
}

// ---------------- prep0: embed->bf16 x[1024][384], WihFB_bf[2048][384], biasFB[2048] ----------------
__global__ void k_prep0(const int* __restrict__ tok, const int* __restrict__ pos,
                        const float* __restrict__ emb, const float* __restrict__ pemb,
                        const float* __restrict__ WihF, const float* __restrict__ WihB,
                        const float* __restrict__ bF, const float* __restrict__ bB,
                        ushort* __restrict__ x, ushort* __restrict__ WihFB,
                        float* __restrict__ biasFB) {
    int i = blockIdx.x * 256 + threadIdx.x;
    const int N0 = Bn * Ln * KPAD;            // 393216
    const int N1 = N0 + G2 * KPAD;            // + 786432
    if (i < N0) {
        int bl = i / KPAD, c = i - bl * KPAD;
        float v = 0.f;
        if (c < EMBc) v = emb[tok[bl] * EMBc + c];
        else if (c < INc) v = pemb[pos[bl] * POSc + (c - EMBc)];
        x[i] = b16rne(v);
    } else if (i < N1) {
        int w = i - N0;
        int r = w / KPAD, c = w - r * KPAD;
        float v = 0.f;
        if (c < INc) v = (r < G4) ? WihF[(size_t)r * INc + c] : WihB[(size_t)(r - G4) * INc + c];
        WihFB[w] = b16rne(v);
    } else if (i < N1 + G2) {
        int j = i - N1;
        biasFB[j] = (j < G4) ? bF[j] : bB[j - G4];
    }
}

// ---------------- MFMA bf16 GEMM: C[M,N] = A[M,K] @ B[N,K]^T + bias ----------------
__global__ __launch_bounds__(256) void k_gemm_bf(
    const ushort* __restrict__ A, const ushort* __restrict__ B,
    const float* __restrict__ bias, float* __restrict__ C, int M, int N, int K) {
    __shared__ __align__(16) ushort As[64][72];
    __shared__ __align__(16) ushort Bs[64][72];
    int tid = threadIdx.x;
    int lane = tid & 63, wv = tid >> 6;
    int m0 = blockIdx.y * 64, n0 = blockIdx.x * 64;
    int mw = (wv >> 1) * 32, nw = (wv & 1) * 32;
    int lr16 = lane & 15, g4 = lane >> 4;
    f32x4 acc[2][2] = {};
    for (int k0 = 0; k0 < K; k0 += 64) {
#pragma unroll
        for (int it = 0; it < 2; it++) {
            int idx = tid + it * 256;
            int r = idx >> 3, ch = idx & 7;
            uint4 av = *(const uint4*)(A + (size_t)(m0 + r) * K + k0 + ch * 8);
            *(uint4*)(&As[r][ch * 8]) = av;
            uint4 bv2 = *(const uint4*)(B + (size_t)(n0 + r) * K + k0 + ch * 8);
            *(uint4*)(&Bs[r][ch * 8]) = bv2;
        }
        __syncthreads();
#pragma unroll
        for (int ks = 0; ks < 2; ks++) {
            bf16x8 af[2], bfr[2];
#pragma unroll
            for (int i = 0; i < 2; i++) {
                af[i]  = *(const bf16x8*)(&As[mw + i * 16 + lr16][ks * 32 + g4 * 8]);
                bfr[i] = *(const bf16x8*)(&Bs[nw + i * 16 + lr16][ks * 32 + g4 * 8]);
            }
#pragma unroll
            for (int i = 0; i < 2; i++)
#pragma unroll
                for (int j = 0; j < 2; j++)
                    acc[i][j] = __builtin_amdgcn_mfma_f32_16x16x32_bf16(af[i], bfr[j], acc[i][j], 0, 0, 0);
        }
        __syncthreads();
    }
#pragma unroll
    for (int i = 0; i < 2; i++)
#pragma unroll
        for (int j = 0; j < 2; j++)
#pragma unroll
            for (int r2 = 0; r2 < 4; r2++) {
                int mm = m0 + mw + i * 16 + g4 * 4 + r2;
                int nn = n0 + nw + j * 16 + lr16;
                C[(size_t)mm * N + nn] = acc[i][j][r2] + (bias ? bias[nn] : 0.f);
            }
}

// ---------------- bidirectional masked LSTM + hidden round-weight prep ----------------
// Blocks 0-7: LSTM (d = blk>>2, q = blk&3), 512 threads, weights in VGPRs, tagged-u64
// h-exchange via agent-scope atomics. Blocks 8-39: f2b prep for round weights
// (runs concurrently on otherwise-idle CUs).
__global__ __launch_bounds__(512) void k_lstm_mfma(
    const float* __restrict__ Xpre,           // [1024][2048]
    const float* __restrict__ WhhF, const float* __restrict__ WhhB,
    const float* __restrict__ mask, float* __restrict__ Henc,
    ushort* __restrict__ HencB, unsigned long long* __restrict__ hG,
    const float* __restrict__ Wg_hh, const float* __restrict__ Wr_hh,
    const float* __restrict__ W_Lr, const float* __restrict__ bg_hh,
    const float* __restrict__ br_hh,
    ushort* __restrict__ WhhGR, ushort* __restrict__ WLrAB, float* __restrict__ biasGR) {
    const int blk = blockIdx.x;
    const int tid = threadIdx.x;

    if (blk >= 8) {
        // ---- prep path ----
        const int stride = 32 * 512;
        int pid = (blk - 8) * 512 + tid;
        for (int idx = pid; idx < GHW * H2c; idx += stride) {
            int r = idx >> 9, c = idx & 511;
            float v = (r < G3) ? Wg_hh[(size_t)r * H2c + c] : Wr_hh[(size_t)(r - G3) * H2c + c];
            WhhGR[idx] = b16rne(v);
        }
        for (int idx = pid; idx < G4 * H2c; idx += stride) {
            int r = idx >> 9, c = idx & 511;
            float v = (r < H2c) ? W_Lr[(size_t)r * (2 * H2c) + c]
                                : W_Lr[(size_t)(r - H2c) * (2 * H2c) + H2c + c];
            WLrAB[idx] = b16rne(v);
        }
        for (int idx = pid; idx < GHW; idx += stride)
            biasGR[idx] = (idx < G3) ? bg_hh[idx] : br_hh[idx - G3];
        return;
    }

    const int d = blk >> 2, q = blk & 3;
    const float* Whh = d ? WhhB : WhhF;
    const int lane = tid & 63, wv = tid >> 6;
    const int lr16 = lane & 15, g4 = lane >> 4;

    __shared__ __align__(16) uint32_t hlds[2][8 * 136];  // double-buffered, stride 136
    __shared__ float Glds[256][9];

    // ---- weights -> registers (fp32 -> bf16 RNE) ----
    bf16x8 aw[16];
#pragma unroll
    for (int jt2 = 0; jt2 < 2; jt2++) {
        int jt = wv * 2 + jt2;
        int lr = jt * 16 + lr16;
        int g = lr >> 6, jj = lr & 63;
        int R = g * 256 + q * 64 + jj;
        const float* wr = Whh + (size_t)R * 256;
#pragma unroll
        for (int kt = 0; kt < 8; kt++) {
            int k0 = kt * 32 + g4 * 8;
            float4 f0 = *(const float4*)(wr + k0);
            float4 f1 = *(const float4*)(wr + k0 + 4);
            bf16x8 a;
            a[0] = (short)b16rne(f0.x); a[1] = (short)b16rne(f0.y);
            a[2] = (short)b16rne(f0.z); a[3] = (short)b16rne(f0.w);
            a[4] = (short)b16rne(f1.x); a[5] = (short)b16rne(f1.y);
            a[6] = (short)b16rne(f1.z); a[7] = (short)b16rne(f1.w);
            aw[jt2 * 8 + kt] = a;
        }
    }

    const int jj_t = tid & 63, b_t = tid >> 6;
    float hval = 0.f, cval = 0.f;
    const int bcol = lane & 15;
    const int bb = lane & 7;
    const int u1 = tid + 512;

    for (int s = 0; s < Ln; s++) {
        const int t = d ? (Ln - 1 - s) : s;

        const float* xrow = Xpre + ((size_t)(b_t * Ln + t)) * G2 + d * G4 + q * 64 + jj_t;
        float xg0 = xrow[0], xg1 = xrow[256], xg2 = xrow[512], xg3 = xrow[768];
        float mval = mask[b_t * Ln + t];

        // ---- poll 2 tagged u64 units (tag == s); memset(0) covers s=0 ----
        const unsigned long long* slot = hG + ((size_t)(s & 1) * 2 + d) * 1024;
        unsigned long long ea, eb;
        do {
            ea = __hip_atomic_load(slot + tid, __ATOMIC_RELAXED, __HIP_MEMORY_SCOPE_AGENT);
            eb = __hip_atomic_load(slot + u1,  __ATOMIC_RELAXED, __HIP_MEMORY_SCOPE_AGENT);
        } while ((unsigned)(ea >> 32) != (unsigned)s || (unsigned)(eb >> 32) != (unsigned)s);
        uint32_t* hb = hlds[s & 1];
        hb[(tid >> 7) * 136 + (tid & 127)] = (uint32_t)ea;
        hb[(u1 >> 7) * 136 + (u1 & 127)]  = (uint32_t)eb;
        __syncthreads();                       // A: stage-write -> ds_read

        bf16x8 bv[8];
#pragma unroll
        for (int kt = 0; kt < 8; kt++)
            bv[kt] = *(const bf16x8*)(&hb[bb * 136 + kt * 16 + g4 * 4]);

        f32x4 acc0 = {0.f, 0.f, 0.f, 0.f}, acc1 = {0.f, 0.f, 0.f, 0.f};
#pragma unroll
        for (int kt = 0; kt < 8; kt++) {
            acc0 = __builtin_amdgcn_mfma_f32_16x16x32_bf16(aw[kt], bv[kt], acc0, 0, 0, 0);
            acc1 = __builtin_amdgcn_mfma_f32_16x16x32_bf16(aw[8 + kt], bv[kt], acc1, 0, 0, 0);
        }

        if (bcol < 8) {
            int lrb0 = (wv * 2 + 0) * 16 + g4 * 4;
            int lrb1 = (wv * 2 + 1) * 16 + g4 * 4;
#pragma unroll
            for (int r2 = 0; r2 < 4; r2++) Glds[lrb0 + r2][bcol] = acc0[r2];
#pragma unroll
            for (int r2 = 0; r2 < 4; r2++) Glds[lrb1 + r2][bcol] = acc1[r2];
        }
        __syncthreads();                       // B: Glds write -> read

        float iv = sigf(xg0 + Glds[jj_t][b_t]);
        float fv = sigf(xg1 + Glds[64 + jj_t][b_t]);
        float gv = tanhf(xg2 + Glds[128 + jj_t][b_t]);
        float ov = sigf(xg3 + Glds[192 + jj_t][b_t]);
        float cn = fv * cval + iv * gv;
        float hn = ov * tanhf(cn);
        float hv = mval * hn + (1.f - mval) * hval;
        cval = mval * cn + (1.f - mval) * cval;
        hval = hv;

        // ---- publish FIRST (critical path), then Henc stores ----
        int hbits = (int)b16rne(hv);
        int pbits = __shfl_xor(hbits, 1);
        if ((jj_t & 1) == 0) {
            uint32_t dataw = ((uint32_t)hbits & 0xFFFFu) | ((uint32_t)pbits << 16);
            unsigned long long word = ((unsigned long long)(unsigned)(s + 1) << 32) | dataw;
            __hip_atomic_store(hG + ((size_t)((s + 1) & 1) * 2 + d) * 1024 +
                                   b_t * 128 + q * 32 + (jj_t >> 1),
                               word, __ATOMIC_RELAXED, __HIP_MEMORY_SCOPE_AGENT);
        }
        float ho = hv * mval;
        size_t hidx = ((size_t)(b_t * Ln + t)) * H2c + d * Hc + q * 64 + jj_t;
        Henc[hidx] = ho;
        HencB[hidx] = b16rne(ho);
        // no end barrier: hlds double-buffered; Glds protected by A/B barriers
    }
}

// ---------------- proj9: out[1024][9] = H[1024][512] @ W[9][512]^T + b ----------------
// wave per row, 4 waves/block
__global__ __launch_bounds__(256) void k_proj9(
    const float* __restrict__ H, const float* __restrict__ W,
    const float* __restrict__ b, float* __restrict__ out) {
    int lane = threadIdx.x & 63, wv = threadIdx.x >> 6;
    int row = blockIdx.x * 4 + wv;
    const float4* h4 = (const float4*)(H + (size_t)row * H2c + lane * 8);
    float4 h0 = h4[0], h1 = h4[1];
    float acc[NBIOc];
#pragma unroll
    for (int k = 0; k < NBIOc; k++) {
        const float4* w4 = (const float4*)(W + (size_t)k * H2c + lane * 8);
        float4 w0 = w4[0], w1 = w4[1];
        acc[k] = h0.x * w0.x + h0.y * w0.y + h0.z * w0.z + h0.w * w0.w +
                 h1.x * w1.x + h1.y * w1.y + h1.z * w1.z + h1.w * w1.w;
    }
#pragma unroll
    for (int off = 32; off >= 1; off >>= 1)
#pragma unroll
        for (int k = 0; k < NBIOc; k++) acc[k] += __shfl_down(acc[k], off);
    if (lane == 0) {
#pragma unroll
        for (int k = 0; k < NBIOc; k++) out[(size_t)row * NBIOc + k] = acc[k] + b[k];
    }
}

// ---------------- log_softmax * mask ----------------
__global__ void k_logsoftmax9(const float* __restrict__ lg, const float* __restrict__ mask,
                              float* __restrict__ outp) {
    int r = blockIdx.x * 256 + threadIdx.x;
    if (r >= Bn * Ln) return;
    float v[NBIOc], mx = -3.4e38f;
#pragma unroll
    for (int k = 0; k < NBIOc; k++) { v[k] = lg[r * NBIOc + k]; mx = fmaxf(mx, v[k]); }
    float s = 0.f;
#pragma unroll
    for (int k = 0; k < NBIOc; k++) s += __expf(v[k] - mx);
    float lse = mx + __logf(s);
    float m = mask[r];
#pragma unroll
    for (int k = 0; k < NBIOc; k++) outp[r * NBIOc + k] = (v[k] - lse) * m;
}

// ---------------- pair scores with masked max over t; C[1024][1024] = [a | b2] ----------------
__global__ __launch_bounds__(128) void k_pairmax(
    const float* __restrict__ Cp, const float* __restrict__ bL,
    const float* __restrict__ WCr, const float* __restrict__ bCr,
    const float* __restrict__ mask, float* __restrict__ probCr) {
    int bs = blockIdx.x;
    int b = bs >> 7;
    __shared__ __align__(16) float As[H2c];
    __shared__ __align__(16) float Ws[NLABc][H2c];
    __shared__ float red[NLABc][128];
    int tid = threadIdx.x;
    for (int i = tid; i < H2c; i += 128) As[i] = Cp[(size_t)bs * G4 + i] + bL[i];
    for (int i = tid; i < NLABc * H2c; i += 128) Ws[i / H2c][i % H2c] = WCr[i];
    __syncthreads();
    int t = tid;
    float m3 = mask[bs] * mask[b * Ln + t];
    float outv[NLABc];
    if (m3 > 0.f) {
        float4 acc[NLABc];
#pragma unroll
        for (int k = 0; k < NLABc; k++) acc[k] = make_float4(0.f, 0.f, 0.f, 0.f);
        const float4* B4 = (const float4*)(Cp + (size_t)(b * Ln + t) * G4 + H2c);
        const float4* A4 = (const float4*)As;
        for (int qq = 0; qq < H2c / 4; qq++) {
            float4 a = A4[qq], bb = B4[qq];
            float4 e;
            e.x = fmaxf(a.x + bb.x, 0.f);
            e.y = fmaxf(a.y + bb.y, 0.f);
            e.z = fmaxf(a.z + bb.z, 0.f);
            e.w = fmaxf(a.w + bb.w, 0.f);
#pragma unroll
            for (int k = 0; k < NLABc; k++) {
                float4 w = *(const float4*)(&Ws[k][qq * 4]);
                acc[k].x += e.x * w.x; acc[k].y += e.y * w.y;
                acc[k].z += e.z * w.z; acc[k].w += e.w * w.w;
            }
        }
#pragma unroll
        for (int k = 0; k < NLABc; k++)
            outv[k] = sigf(acc[k].x + acc[k].y + acc[k].z + acc[k].w + bCr[k]);
    } else {
#pragma unroll
        for (int k = 0; k < NLABc; k++) outv[k] = NEGc;
    }
#pragma unroll
    for (int k = 0; k < NLABc; k++) red[k][tid] = outv[k];
    __syncthreads();
    for (int off = 64; off >= 1; off >>= 1) {
        if (tid < off) {
#pragma unroll
            for (int k = 0; k < NLABc; k++) red[k][tid] = fmaxf(red[k][tid], red[k][tid + off]);
        }
        __syncthreads();
    }
    if (tid < NLABc) probCr[bs * NLABc + tid] = red[tid][0];
}

// ---------------- full pair scores * m3 (final output) ----------------
__global__ __launch_bounds__(128) void k_pairfull(
    const float* __restrict__ Cp, const float* __restrict__ bL,
    const float* __restrict__ WCr, const float* __restrict__ bCr,
    const float* __restrict__ mask, float* __restrict__ outCr) {
    int bs = blockIdx.x;
    int b = bs >> 7;
    __shared__ __align__(16) float As[H2c];
    __shared__ __align__(16) float Ws[NLABc][H2c];
    int tid = threadIdx.x;
    for (int i = tid; i < H2c; i += 128) As[i] = Cp[(size_t)bs * G4 + i] + bL[i];
    for (int i = tid; i < NLABc * H2c; i += 128) Ws[i / H2c][i % H2c] = WCr[i];
    __syncthreads();
    int t = tid;
    float m3 = mask[bs] * mask[b * Ln + t];
    float outv[NLABc];
    if (m3 > 0.f) {
        float4 acc[NLABc];
#pragma unroll
        for (int k = 0; k < NLABc; k++) acc[k] = make_float4(0.f, 0.f, 0.f, 0.f);
        const float4* B4 = (const float4*)(Cp + (size_t)(b * Ln + t) * G4 + H2c);
        const float4* A4 = (const float4*)As;
        for (int qq = 0; qq < H2c / 4; qq++) {
            float4 a = A4[qq], bb = B4[qq];
            float4 e;
            e.x = fmaxf(a.x + bb.x, 0.f);
            e.y = fmaxf(a.y + bb.y, 0.f);
            e.z = fmaxf(a.z + bb.z, 0.f);
            e.w = fmaxf(a.w + bb.w, 0.f);
#pragma unroll
            for (int k = 0; k < NLABc; k++) {
                float4 w = *(const float4*)(&Ws[k][qq * 4]);
                acc[k].x += e.x * w.x; acc[k].y += e.y * w.y;
                acc[k].z += e.z * w.z; acc[k].w += e.w * w.w;
            }
        }
#pragma unroll
        for (int k = 0; k < NLABc; k++)
            outv[k] = sigf(acc[k].x + acc[k].y + acc[k].z + acc[k].w + bCr[k]);
    } else {
#pragma unroll
        for (int k = 0; k < NLABc; k++) outv[k] = 0.f;
    }
    size_t base = ((size_t)bs * Ln + t) * NLABc;
#pragma unroll
    for (int k = 0; k < NLABc; k++) outCr[base + k] = outv[k];
}

// ---------------- fused double GRU: softmax(cg) inline, both ih projections,
//                  Hg, Hr, Hc = hp + hr + hg, bf16 mirrors ----------------
__global__ void k_gru2(const float* __restrict__ gh /*[1024][3072]*/,
                       const float* __restrict__ cg, const float* __restrict__ pCr,
                       const float* __restrict__ Wg_ih, const float* __restrict__ bg_ih,
                       const float* __restrict__ Wr_ih, const float* __restrict__ br_ih,
                       const float* __restrict__ hprev,
                       float* __restrict__ Hg_out, float* __restrict__ Hcb_out,
                       ushort* __restrict__ Hrb_out, ushort* __restrict__ Hcbb_out) {
    int i = blockIdx.x * 256 + threadIdx.x;
    if (i >= Bn * Ln * H2c) return;
    int m = i >> 9, j = i & 511;

    // softmax over cg[m][0..8]
    float v[NBIOc], mx = -3.4e38f;
#pragma unroll
    for (int k = 0; k < NBIOc; k++) { v[k] = cg[m * NBIOc + k]; mx = fmaxf(mx, v[k]); }
    float ssum = 0.f;
#pragma unroll
    for (int k = 0; k < NBIOc; k++) { v[k] = __expf(v[k] - mx); ssum += v[k]; }
    float inv = 1.f / ssum;

    // g-GRU ih projection (input = softmax probs)
    float gr = bg_ih[j], gz = bg_ih[H2c + j], gn = bg_ih[2 * H2c + j];
#pragma unroll
    for (int k = 0; k < NBIOc; k++) {
        float pv = v[k] * inv;
        gr += Wg_ih[(size_t)j * NBIOc + k] * pv;
        gz += Wg_ih[(size_t)(H2c + j) * NBIOc + k] * pv;
        gn += Wg_ih[(size_t)(2 * H2c + j) * NBIOc + k] * pv;
    }
    const float* g1 = gh + (size_t)m * GHW;
    float hp = hprev[i];
    float r1 = sigf(gr + g1[j]);
    float z1 = sigf(gz + g1[H2c + j]);
    float n1 = tanhf(gn + r1 * g1[2 * H2c + j]);
    float hg = (1.f - z1) * n1 + z1 * hp;

    // r-GRU ih projection (input = pCr)
    float rr = br_ih[j], rz = br_ih[H2c + j], rn = br_ih[2 * H2c + j];
    const float* p = pCr + (size_t)m * NLABc;
#pragma unroll
    for (int k = 0; k < NLABc; k++) {
        float pv = p[k];
        rr += Wr_ih[(size_t)j * NLABc + k] * pv;
        rz += Wr_ih[(size_t)(H2c + j) * NLABc + k] * pv;
        rn += Wr_ih[(size_t)(2 * H2c + j) * NLABc + k] * pv;
    }
    const float* g2 = g1 + G3;
    float r2 = sigf(rr + g2[j]);
    float z2 = sigf(rz + g2[H2c + j]);
    float n2 = tanhf(rn + r2 * g2[2 * H2c + j]);
    float hr = (1.f - z2) * n2 + z2 * hp;

    float hc = hp + hr + hg;
    Hg_out[i] = hg;
    Hcb_out[i] = hc;
    Hrb_out[i] = b16rne(hr);
    Hcbb_out[i] = b16rne(hc);
}

extern "C" void kernel_launch(void* const* d_in, const int* in_sizes, int n_in,
                              void* d_out, int out_size, void* d_ws, size_t ws_size,
                              hipStream_t stream) {
    const int*   tok   = (const int*)d_in[0];
    const int*   pos   = (const int*)d_in[1];
    const float* mask  = (const float*)d_in[2];
    const float* emb   = (const float*)d_in[3];
    const float* pemb  = (const float*)d_in[4];
    const float* WihF  = (const float*)d_in[5];
    const float* WhhF  = (const float*)d_in[6];
    const float* bF    = (const float*)d_in[7];
    const float* WihB  = (const float*)d_in[8];
    const float* WhhB  = (const float*)d_in[9];
    const float* bB    = (const float*)d_in[10];
    const float* Wg_ih = (const float*)d_in[11];
    const float* Wg_hh = (const float*)d_in[12];
    const float* bg_ih = (const float*)d_in[13];
    const float* bg_hh = (const float*)d_in[14];
    const float* Wr_ih = (const float*)d_in[15];
    const float* Wr_hh = (const float*)d_in[16];
    const float* br_ih = (const float*)d_in[17];
    const float* br_hh = (const float*)d_in[18];
    const float* W_Lr  = (const float*)d_in[19];
    const float* b_Lr  = (const float*)d_in[20];
    const float* W_Cr  = (const float*)d_in[21];
    const float* b_Cr  = (const float*)d_in[22];
    const float* W_Cg  = (const float*)d_in[23];
    const float* b_Cg  = (const float*)d_in[24];

    float* outp = (float*)d_out;
    float* ws = (float*)d_ws;

    // exchange buffer: hG[2 slots][2 dir][1024] u64 = 32KB
    unsigned long long* hG = (unsigned long long*)ws;
    size_t off = 8192;
    auto alloc = [&](size_t n) { off = (off + 3) & ~(size_t)3; float* p = ws + off; off += n; return p; };
    auto allocU = [&](size_t n_us) { off = (off + 3) & ~(size_t)3; ushort* p = (ushort*)(ws + off); off += (n_us + 1) / 2; return p; };

    // R1: Xpre [1024][2048] (setup/LSTM) -> pairC [1024][1024] / gh [1024][3072] (rounds)
    float* R1 = alloc((size_t)G4 * GHW);      // 3,145,728 floats
    float* Xpre  = R1;
    float* pairC = R1;
    float* gh    = R1;
    // WihFB_bf + x_bf aliased into R1 tail (dead before gh is first written)
    ushort* WihFB_bf = (ushort*)(R1 + (size_t)G4 * G2);                  // 786432 us
    ushort* x_bf     = (ushort*)(R1 + (size_t)G4 * G2 + 393216);         // 393216 us
    float*  biasFB   = R1 + (size_t)G4 * G2 + 393216 + 196608;           // 2048 f

    ushort* WhhGR_bf = allocU((size_t)GHW * H2c);
    ushort* WLrAB_bf = allocU((size_t)G4 * H2c);
    float*  biasGR   = alloc(GHW);
    float*  Henc     = alloc((size_t)Bn * Ln * H2c);
    ushort* Henc_bf  = allocU((size_t)Bn * Ln * H2c);
    float*  Hg       = alloc((size_t)Bn * Ln * H2c);
    float*  Hcb      = alloc((size_t)Bn * Ln * H2c);
    ushort* Hr_bf    = allocU((size_t)Bn * Ln * H2c);
    ushort* Hcb_bf   = allocU((size_t)Bn * Ln * H2c);
    float*  cg       = alloc((size_t)Bn * Ln * NBIOc);
    float*  pCr      = alloc((size_t)Bn * Ln * NLABc);
    (void)ws_size; (void)in_sizes; (void)n_in; (void)out_size;

    auto gemm_bf = [&](const ushort* A, const ushort* B, const float* bias,
                       float* C, int M, int N, int K) {
        dim3 g(N / 64, M / 64);
        k_gemm_bf<<<g, 256, 0, stream>>>(A, B, bias, C, M, N, K);
    };

    // --- reset exchange buffer ---
    hipMemsetAsync(hG, 0, 8192 * sizeof(float), stream);

    // --- prep0: embed + input-proj weights/bias ---
    {
        int total = Bn * Ln * KPAD + G2 * KPAD + G2;
        k_prep0<<<(total + 255) / 256, 256, 0, stream>>>(
            tok, pos, emb, pemb, WihF, WihB, bF, bB, x_bf, WihFB_bf, biasFB);
    }

    // --- combined input projection: Xpre [1024][2048] ---
    gemm_bf(x_bf, WihFB_bf, biasFB, Xpre, Bn * Ln, G2, KPAD);

    // --- LSTM (8 blocks) + concurrent round-weight prep (32 blocks) ---
    k_lstm_mfma<<<40, 512, 0, stream>>>(Xpre, WhhF, WhhB, mask, Henc, Henc_bf, hG,
                                        Wg_hh, Wr_hh, W_Lr, bg_hh, br_hh,
                                        WhhGR_bf, WLrAB_bf, biasGR);

    // --- message-passing rounds ---
    const float*  Hgs    = Henc;
    const ushort* Hrs_bf = Henc_bf;
    const float*  Hcs    = Henc;
    const ushort* Hcs_bf = Henc_bf;
    for (int r = 0; r < 2; r++) {
        k_proj9<<<Bn * Ln / 4, 256, 0, stream>>>(Hgs, W_Cg, b_Cg, cg);

        gemm_bf(Hrs_bf, WLrAB_bf, nullptr, pairC, Bn * Ln, G4, H2c);
        k_pairmax<<<Bn * Ln, 128, 0, stream>>>(pairC, b_Lr, W_Cr, b_Cr, mask, pCr);

        gemm_bf(Hcs_bf, WhhGR_bf, biasGR, gh, Bn * Ln, GHW, H2c);
        k_gru2<<<(Bn * Ln * H2c + 255) / 256, 256, 0, stream>>>(
            gh, cg, pCr, Wg_ih, bg_ih, Wr_ih, br_ih, Hcs, Hg, Hcb, Hr_bf, Hcb_bf);

        Hgs = Hg; Hrs_bf = Hr_bf; Hcs = Hcb; Hcs_bf = Hcb_bf;
    }

    // --- final outputs ---
    k_proj9<<<Bn * Ln / 4, 256, 0, stream>>>(Hgs, W_Cg, b_Cg, cg);
    k_logsoftmax9<<<4, 256, 0, stream>>>(cg, mask, outp);

    gemm_bf(Hrs_bf, WLrAB_bf, nullptr, pairC, Bn * Ln, G4, H2c);
    k_pairfull<<<Bn * Ln, 128, 0, stream>>>(pairC, b_Lr, W_Cr, b_Cr, mask,
                                            outp + Bn * Ln * NBIOc);
}